// Round 10
// baseline (2841.588 us; speedup 1.0000x reference)
//
#include <hip/hip_runtime.h>
#include <hip/hip_cooperative_groups.h>

namespace cg = cooperative_groups;

#define DEV __device__ __forceinline__

typedef _Float16 f16;
typedef _Float16 f16x8 __attribute__((ext_vector_type(8)));
typedef _Float16 f16x2 __attribute__((ext_vector_type(2)));
typedef float f32x4 __attribute__((ext_vector_type(4)));

DEV float sigmoidf_(float x) { return 1.0f / (1.0f + __expf(-x)); }
DEV float tanhf2_(float x)   { return 1.0f - 2.0f / (__expf(2.0f * x) + 1.0f); }

// async global->LDS, 16B per lane. LDS dest = wave-uniform base + lane*16.
DEV void load_lds16(const void* g, void* l) {
    __builtin_amdgcn_global_load_lds(
        (const __attribute__((address_space(1))) char*)(const char*)g,
        (__attribute__((address_space(3))) char*)(unsigned int)(unsigned long long)(char*)l,
        16, 0, 0);
}

// LDS 16x32(f16) tile swizzle: chunk (row,ck) lives at physical slot
// ck ^ (row&3) ^ ((row>>2)&3). Loader permutes the GLOBAL chunk per lane;
// reader picks the matching physical slot (XOR involution).
DEV int swz(int row, int ck) { return ck ^ (row & 3) ^ ((row >> 2) & 3); }

// ---------------------------------------------------------------------------
// LSTM weight prep: Wt[1024][K] fp16, column-order chosen so that in the MFMA
// C-layout the 4 gates of a unit land in one lane's 4 j-fragments.
// dst row rd: T=rd>>7, p=rd&127, wh=(p>>6)&1, j=(p>>4)&3, c=p&15
//   unit u = T*32 + wh*16 + c ; gate g = j ; src row = g*256+u
// W0t: [1024,288] — cols 0..15 x, 16..271 h0, 272..287 zero (pad to K%32==0)
// ---------------------------------------------------------------------------
__global__ void prep_w0_kernel(const float* __restrict__ wih,
                               const float* __restrict__ whh,
                               f16* __restrict__ dst) {   // [1024,288]
    int idx = blockIdx.x * 256 + threadIdx.x;
    if (idx >= 1024 * 288) return;
    int rd = idx / 288, k = idx - rd * 288;
    int T = rd >> 7, p = rd & 127;
    int u = T * 32 + ((p >> 6) & 1) * 16 + (p & 15);
    int g = (p >> 4) & 3;
    int src = g * 256 + u;
    float v;
    if (k < 16)        v = wih[src * 16 + k];
    else if (k < 272)  v = whh[src * 256 + (k - 16)];
    else               v = 0.f;
    dst[idx] = (f16)v;
}

__global__ void prep_w1_kernel(const float* __restrict__ wih,
                               const float* __restrict__ whh,
                               f16* __restrict__ dst) {   // [1024,512]
    int idx = blockIdx.x * 256 + threadIdx.x;
    if (idx >= 1024 * 512) return;
    int rd = idx >> 9, k = idx & 511;
    int T = rd >> 7, p = rd & 127;
    int u = T * 32 + ((p >> 6) & 1) * 16 + (p & 15);
    int g = (p >> 4) & 3;
    int src = g * 256 + u;
    float v = (k < 256) ? wih[src * 256 + k] : whh[src * 256 + (k - 256)];
    dst[idx] = (f16)v;
}

__global__ void prep_bias4_kernel(const float* __restrict__ bi,
                                  const float* __restrict__ bh,
                                  float* __restrict__ dst) {  // [1024] = [u*4+g]
    int idx = blockIdx.x * 256 + threadIdx.x;
    if (idx >= 1024) return;
    int u = idx >> 2, g = idx & 3;
    dst[idx] = bi[g * 256 + u] + bh[g * 256 + u];
}

// generic [K,N] fp32 -> [N,K] fp16 transpose
__global__ void prep_wt_kernel(const float* __restrict__ src, f16* __restrict__ dst,
                               int K, int N) {
    int idx = blockIdx.x * 256 + threadIdx.x;
    if (idx >= K * N) return;
    int n = idx / K, k = idx - n * K;
    dst[idx] = (f16)src[(size_t)k * N + n];
}

// x_seq[:,0,:16] -> A0buf0 cols 0..15 (lda 288)
__global__ void prep_x0_kernel(const float* __restrict__ x_seq, f16* __restrict__ A0,
                               int Nn) {
    int idx = blockIdx.x * 256 + threadIdx.x;
    if (idx >= Nn * 16) return;
    int m = idx >> 4, f = idx & 15;
    A0[(size_t)m * 288 + f] = (f16)x_seq[(size_t)m * 960 + f];
}

// ---------------------------------------------------------------------------
// Shared MFMA helpers (32-col chunk of a 128x128 tile)
// ---------------------------------------------------------------------------
DEV void tile_load_chunk(const f16* __restrict__ A, int lda,
                         const f16* __restrict__ Bt, int K,
                         int m0, int n0, int k0,
                         f16* __restrict__ sA, f16* __restrict__ sB,
                         int w, int arow, int achk)
{
#pragma unroll
    for (int c = 0; c < 2; ++c) {
        int R = c * 64 + w * 16;
        load_lds16(A + (size_t)(m0 + R + arow) * lda + k0 + achk, sA + R * 32);
        load_lds16(Bt + (size_t)(n0 + R + arow) * K + k0 + achk, sB + R * 32);
    }
}

DEV void tile_compute_chunk(const f16* __restrict__ sA, const f16* __restrict__ sB,
                            f32x4 (&acc)[4][4], int wr, int wc, int frow, int fsl)
{
    f16x8 af[4], bf[4];
#pragma unroll
    for (int i = 0; i < 4; ++i)
        af[i] = *(const f16x8*)&sA[(wr + i * 16 + frow) * 32 + fsl];
#pragma unroll
    for (int j = 0; j < 4; ++j)
        bf[j] = *(const f16x8*)&sB[(wc + j * 16 + frow) * 32 + fsl];
#pragma unroll
    for (int i = 0; i < 4; ++i)
#pragma unroll
        for (int j = 0; j < 4; ++j)
            acc[i][j] = __builtin_amdgcn_mfma_f32_16x16x32_f16(af[i], bf[j], acc[i][j], 0, 0, 0);
}

// ---------------------------------------------------------------------------
// Tile GEMM core (R4-proven): 128x128 tile, 4 waves 2x2, TRIPLE-buffered
// 32-col chunks with depth-2 prefetch and counted vmcnt:
//   iter kc: s_waitcnt vmcnt(4)  <- chunk kc landed; kc+1 stays in flight
//            s_barrier           <- all waves' writes visible
//            issue chunk kc+2    <- into buf freed at iter kc-1
//            ds_read+MFMA chunk kc
// ---------------------------------------------------------------------------
DEV void gemm_tile_lds(const f16* __restrict__ A, int lda,
                       const f16* __restrict__ Bt, int K,
                       int m0, int n0,
                       f16* __restrict__ sA, f16* __restrict__ sB,  // [3*4096]
                       f32x4 (&acc)[4][4])
{
    const int tid = threadIdx.x;
    const int w = tid >> 6, lane = tid & 63;
    const int arow = lane >> 2;
    const int achk = swz(arow, lane & 3) * 8;
    const int frow = lane & 15, l4 = lane >> 4;
    const int fsl = swz(frow, l4) * 8;
    const int wr = (w >> 1) * 64, wc = (w & 1) * 64;
    const int nch = K >> 5;

    tile_load_chunk(A, lda, Bt, K, m0, n0, 0, sA, sB, w, arow, achk);
    if (nch > 1)
        tile_load_chunk(A, lda, Bt, K, m0, n0, 32, sA + 4096, sB + 4096, w, arow, achk);

    int cb = 0, lb = 2;
    for (int kc = 0; kc < nch; ++kc) {
        if (kc + 1 < nch) asm volatile("s_waitcnt vmcnt(4)" ::: "memory");
        else              asm volatile("s_waitcnt vmcnt(0)" ::: "memory");
        __builtin_amdgcn_s_barrier();
        if (kc + 2 < nch)
            tile_load_chunk(A, lda, Bt, K, m0, n0, (kc + 2) * 32,
                            sA + lb * 4096, sB + lb * 4096, w, arow, achk);
        tile_compute_chunk(sA + cb * 4096, sB + cb * 4096, acc, wr, wc, frow, fsl);
        cb = (cb == 2) ? 0 : cb + 1;
        lb = (lb == 2) ? 0 : lb + 1;
    }
}

// ---------------------------------------------------------------------------
// LSTM tile step with REGISTER-RESIDENT c-state (persistent path).
// Same math as legacy core; cst[4][4] is read-modify-write in registers.
// ---------------------------------------------------------------------------
DEV void lstm_tile_step(
    f16* __restrict__ sA, f16* __restrict__ sB,
    int bx, int by,
    const f16* __restrict__ A, int lda, int K,
    const f16* __restrict__ Wt,
    const float* __restrict__ bias4,
    float (&cst)[4][4],
    f16* __restrict__ hA, int ldhA, int offhA,
    f16* __restrict__ hB, int ldhB, int offhB,
    const float* __restrict__ xsrc, int tnext,
    int M)
{
    const int tid = threadIdx.x;
    const int w = tid >> 6, lane = tid & 63;
    const int m0 = bx * 128, n0 = by * 128;
    const int wr = (w >> 1) * 64;
    const int u = by * 32 + (w & 1) * 16 + (lane & 15);
    const int rbase = m0 + wr + (lane >> 4) * 4;

    f32x4 acc[4][4] = {};
    gemm_tile_lds(A, lda, Wt, K, m0, n0, sA, sB, acc);

    const float4 bb = *(const float4*)&bias4[u * 4];
#pragma unroll
    for (int i = 0; i < 4; ++i) {
#pragma unroll
        for (int r = 0; r < 4; ++r) {
            int m = rbase + i * 16 + r;
            if (m < M) {
                float gi = sigmoidf_(acc[i][0][r] + bb.x);
                float gf = sigmoidf_(acc[i][1][r] + bb.y);
                float gg = tanhf2_(acc[i][2][r] + bb.z);
                float go = sigmoidf_(acc[i][3][r] + bb.w);
                float cn = gf * cst[i][r] + gi * gg;
                cst[i][r] = cn;
                f16 h = (f16)(go * tanhf2_(cn));
                hA[(size_t)m * ldhA + offhA + u] = h;
                if (hB) hB[(size_t)m * ldhB + offhB + u] = h;
            }
        }
    }
    if (xsrc && by == 0) {
        int row = tid >> 1, fb = (tid & 1) * 8;
        int m = m0 + row;
        if (m < M) {
            const float* xp = xsrc + (size_t)m * 960 + tnext * 16 + fb;
            f16* dp = hB + (size_t)m * ldhB + fb;
#pragma unroll
            for (int q = 0; q < 8; ++q) dp[q] = (f16)xp[q];
        }
    }
}

// Dispatch one virtual tile (x,y,z) at iteration t. All params block-uniform.
// z=0: L1 at tt=t-1 (active t in 1..60). z=1: L0 at tt=t (active t in 0..59).
DEV void persist_tile(
    f16* __restrict__ sA, f16* __restrict__ sB,
    int x, int y, int z, int t,
    float (&cst)[4][4],
    const f16* __restrict__ W1t, const float* __restrict__ b41,
    const f16* __restrict__ W0t, const float* __restrict__ b40,
    f16* __restrict__ A1b0, f16* __restrict__ A1b1,
    f16* __restrict__ A0b0, f16* __restrict__ A0b1,
    f16* __restrict__ fused, const float* __restrict__ x_seq,
    int M, int mtiles)
{
    if (x >= mtiles) return;
    if (z == 0) {
        if (t < 1) return;
        int tt = t - 1;
        const f16* A = (tt & 1) ? A1b1 : A1b0;
        f16* hA; int ldhA, offhA;
        if (tt == 59) { hA = fused; ldhA = 768; offhA = 0; }
        else { hA = ((tt + 1) & 1) ? A1b1 : A1b0; ldhA = 512; offhA = 256; }
        lstm_tile_step(sA, sB, x, y, A, 512, 512, W1t, b41, cst,
                       hA, ldhA, offhA, nullptr, 0, 0, nullptr, 0, M);
    } else {
        if (t > 59) return;
        int tt = t;
        const f16* A = (tt & 1) ? A0b1 : A0b0;          // [x(tt)|h0(tt-1)|pad]
        f16* hA = (tt & 1) ? A1b1 : A1b0;               // h0(tt) -> cols 0..255
        f16* hB = ((tt + 1) & 1) ? A0b1 : A0b0;         // h0(tt) -> cols 16..271
        lstm_tile_step(sA, sB, x, y, A, 288, 288, W0t, b40, cst,
                       hA, 512, 0, hB, 288, 16,
                       (tt < 59) ? x_seq : nullptr, tt + 1, M);
    }
}

// ---------------------------------------------------------------------------
// PERSISTENT cooperative LSTM: one launch, 61 iterations, grid.sync between.
// Block b owns virtual tiles b and b+nblk (<1280). Tile decode (XCD-swizzled,
// same as legacy): z = v>=640; i = v-z*640; xcd=i&7; q=i>>3; y=q&7;
// x=(q>>3)*8+xcd. With nblk=768: 512 blocks get {one L1 + one L0} tile,
// 256 blocks get one tile. c-state NEVER touches memory (16 VGPR/tile).
// h-flow through A0b/A1b double buffers identical to the legacy launches.
// ---------------------------------------------------------------------------
__global__ __launch_bounds__(256) void lstm_persist_kernel(
    const f16* __restrict__ W1t, const float* __restrict__ b41,
    const f16* __restrict__ W0t, const float* __restrict__ b40,
    f16* __restrict__ A1b0, f16* __restrict__ A1b1,
    f16* __restrict__ A0b0, f16* __restrict__ A0b1,
    f16* __restrict__ fused, const float* __restrict__ x_seq,
    int M, int mtiles, int nblk)
{
    __shared__ __align__(16) f16 sA[3 * 4096];
    __shared__ __align__(16) f16 sB[3 * 4096];
    cg::grid_group grid = cg::this_grid();

    const int b = blockIdx.x;
    int x1, y1, z1;
    { int v = b; z1 = (v >= 640) ? 1 : 0; int i = v - z1 * 640;
      int xcd = i & 7, q = i >> 3; y1 = q & 7; x1 = (q >> 3) * 8 + xcd; }
    const int v2i = b + nblk;
    const bool has2 = v2i < 1280;
    int x2 = 0, y2 = 0, z2 = 0;
    if (has2) { int v = v2i; z2 = (v >= 640) ? 1 : 0; int i = v - z2 * 640;
                int xcd = i & 7, q = i >> 3; y2 = q & 7; x2 = (q >> 3) * 8 + xcd; }

    float cT1[4][4] = {};
    float cT2[4][4] = {};

    for (int t = 0; t <= 60; ++t) {
        persist_tile(sA, sB, x1, y1, z1, t, cT1, W1t, b41, W0t, b40,
                     A1b0, A1b1, A0b0, A0b1, fused, x_seq, M, mtiles);
        __syncthreads();   // LDS reuse hazard between this block's two tiles
        if (has2)
            persist_tile(sA, sB, x2, y2, z2, t, cT2, W1t, b41, W0t, b40,
                         A1b0, A1b1, A0b0, A0b1, fused, x_seq, M, mtiles);
        if (t < 60) grid.sync();
    }
}

// ---------------------------------------------------------------------------
// LEGACY path (fallback if cooperative launch unavailable): c in global.
// ---------------------------------------------------------------------------
DEV void lstm_step_core(
    f16* __restrict__ sA, f16* __restrict__ sB,
    int bx, int by,
    const f16* __restrict__ A, int lda, int K,
    const f16* __restrict__ Wt,
    const float* __restrict__ bias4,
    float* __restrict__ c_state,
    f16* __restrict__ hA, int ldhA, int offhA,
    f16* __restrict__ hB, int ldhB, int offhB,
    const float* __restrict__ xsrc, int tnext,
    int M)
{
    const int tid = threadIdx.x;
    const int w = tid >> 6, lane = tid & 63;
    const int m0 = bx * 128;
    const int wr = (w >> 1) * 64;
    const int u = by * 32 + (w & 1) * 16 + (lane & 15);
    const int rbase = m0 + wr + (lane >> 4) * 4;
    float cold[4][4];
#pragma unroll
    for (int i = 0; i < 4; ++i)
#pragma unroll
        for (int r = 0; r < 4; ++r)
            cold[i][r] = c_state[(size_t)(rbase + i * 16 + r) * 256 + u];

    f32x4 acc[4][4] = {};
    gemm_tile_lds(A, lda, Wt, K, m0, by * 128, sA, sB, acc);

    const float4 bb = *(const float4*)&bias4[u * 4];
#pragma unroll
    for (int i = 0; i < 4; ++i) {
#pragma unroll
        for (int r = 0; r < 4; ++r) {
            int m = rbase + i * 16 + r;
            if (m < M) {
                float gi = sigmoidf_(acc[i][0][r] + bb.x);
                float gf = sigmoidf_(acc[i][1][r] + bb.y);
                float gg = tanhf2_(acc[i][2][r] + bb.z);
                float go = sigmoidf_(acc[i][3][r] + bb.w);
                float cn = gf * cold[i][r] + gi * gg;
                c_state[(size_t)m * 256 + u] = cn;
                f16 h = (f16)(go * tanhf2_(cn));
                hA[(size_t)m * ldhA + offhA + u] = h;
                if (hB) hB[(size_t)m * ldhB + offhB + u] = h;
            }
        }
    }
    if (xsrc && by == 0) {
        int row = tid >> 1, fb = (tid & 1) * 8;
        int m = m0 + row;
        if (m < M) {
            const float* xp = xsrc + (size_t)m * 960 + tnext * 16 + fb;
            f16* dp = hB + (size_t)m * ldhB + fb;
#pragma unroll
            for (int q = 0; q < 8; ++q) dp[q] = (f16)xp[q];
        }
    }
}

__global__ __launch_bounds__(256) void lstm_mfma_kernel(
    const f16* __restrict__ A, int lda, int K,
    const f16* __restrict__ Wt, const float* __restrict__ bias4,
    float* __restrict__ c_state,
    f16* __restrict__ hA, int ldhA, int offhA,
    f16* __restrict__ hB, int ldhB, int offhB,
    const float* __restrict__ xsrc, int tnext, int M, int mtiles)
{
    __shared__ __align__(16) f16 sA[3 * 4096];
    __shared__ __align__(16) f16 sB[3 * 4096];
    const int l = blockIdx.x;
    const int xcd = l & 7, q = l >> 3;
    const int y = q & 7, xhi = q >> 3;
    const int x = xhi * 8 + xcd;
    if (x >= mtiles) return;
    lstm_step_core(sA, sB, x, y, A, lda, K, Wt, bias4, c_state,
                   hA, ldhA, offhA, hB, ldhB, offhB, xsrc, tnext, M);
}

__global__ __launch_bounds__(256) void lstm_dual_kernel(
    const f16* __restrict__ A1, const f16* __restrict__ W1t,
    const float* __restrict__ b41, float* __restrict__ c1,
    f16* __restrict__ h1A, int ldh1A, int offh1A,
    const f16* __restrict__ A0, const f16* __restrict__ W0t,
    const float* __restrict__ b40, float* __restrict__ c0,
    f16* __restrict__ h0A, int ldh0A, int offh0A,
    f16* __restrict__ h0B, int ldh0B, int offh0B,
    const float* __restrict__ xsrc, int tnext, int M, int mtiles)
{
    __shared__ __align__(16) f16 sA[3 * 4096];
    __shared__ __align__(16) f16 sB[3 * 4096];
    const int l = blockIdx.x;
    const int xcd = l & 7, q = l >> 3;
    const int yz = q & 15, xhi = q >> 4;
    const int x = xhi * 8 + xcd;
    if (x >= mtiles) return;
    const int y = yz & 7, z = yz >> 3;
    if (z == 0)
        lstm_step_core(sA, sB, x, y, A1, 512, 512, W1t, b41, c1,
                       h1A, ldh1A, offh1A, nullptr, 0, 0, nullptr, 0, M);
    else
        lstm_step_core(sA, sB, x, y, A0, 288, 288, W0t, b40, c0,
                       h0A, ldh0A, offh0A, h0B, ldh0B, offh0B, xsrc, tnext, M);
}

// ---------------------------------------------------------------------------
// Generic f16 MFMA GEMM (triple-buffered): C = act(A @ Bt^T + bias)
// ---------------------------------------------------------------------------
__global__ __launch_bounds__(256) void gemm16_kernel(
    const f16* __restrict__ A, int lda,
    const f16* __restrict__ Bt, int K,
    const float* __restrict__ bias,
    f16* __restrict__ C16, float* __restrict__ C32, int ldc,
    int act, int M)
{
    __shared__ __align__(16) f16 sA[3 * 4096];
    __shared__ __align__(16) f16 sB[3 * 4096];
    const int tid = threadIdx.x;
    const int w = tid >> 6, lane = tid & 63;
    const int m0 = blockIdx.x * 128, n0 = blockIdx.y * 128;
    const int wr = (w >> 1) * 64, wcn = (w & 1) * 64;

    f32x4 acc[4][4] = {};
    gemm_tile_lds(A, lda, Bt, K, m0, n0, sA, sB, acc);

    const int rbase = m0 + wr + (lane >> 4) * 4;
#pragma unroll
    for (int i = 0; i < 4; ++i) {
#pragma unroll
        for (int r = 0; r < 4; ++r) {
            int m = rbase + i * 16 + r;
            if (m >= M) continue;
#pragma unroll
            for (int j = 0; j < 4; ++j) {
                int n = n0 + wcn + j * 16 + (lane & 15);
                float v = acc[i][j][r] + bias[n];
                if (act == 1) v = fmaxf(v, 0.f);
                if (C16) C16[(size_t)m * ldc + n] = (f16)v;
                else     C32[(size_t)m * ldc + n] = v;
            }
        }
    }
}

// dual-B variant: y<4 -> (Btl,biasl,Cl), y>=4 -> (Btr,biasr,Cr). fp16 out.
__global__ __launch_bounds__(256) void gemm16_dual_kernel(
    const f16* __restrict__ A, int lda,
    const f16* __restrict__ Btl, const f16* __restrict__ Btr, int K,
    const float* __restrict__ biasl, const float* __restrict__ biasr,
    f16* __restrict__ Cl, f16* __restrict__ Cr, int ldc, int M)
{
    __shared__ __align__(16) f16 sA[3 * 4096];
    __shared__ __align__(16) f16 sB[3 * 4096];
    const int side = blockIdx.y >> 2;
    const f16* Bt = side ? Btr : Btl;
    const float* bias = side ? biasr : biasl;
    f16* C16 = side ? Cr : Cl;
    const int tid = threadIdx.x;
    const int w = tid >> 6, lane = tid & 63;
    const int m0 = blockIdx.x * 128, n0 = (blockIdx.y & 3) * 128;
    const int wr = (w >> 1) * 64, wcn = (w & 1) * 64;

    f32x4 acc[4][4] = {};
    gemm_tile_lds(A, lda, Bt, K, m0, n0, sA, sB, acc);

    const int rbase = m0 + wr + (lane >> 4) * 4;
#pragma unroll
    for (int i = 0; i < 4; ++i) {
#pragma unroll
        for (int r = 0; r < 4; ++r) {
            int m = rbase + i * 16 + r;
            if (m >= M) continue;
#pragma unroll
            for (int j = 0; j < 4; ++j) {
                int n = n0 + wcn + j * 16 + (lane & 15);
                float v = acc[i][j][r] + bias[n];
                C16[(size_t)m * ldc + n] = (f16)v;
            }
        }
    }
}

// ---------------------------------------------------------------------------
// Edge preprocessing
// ---------------------------------------------------------------------------
__global__ void mean_sum_kernel(const float* __restrict__ a, int n, float* __restrict__ out) {
    __shared__ float s[256];
    float loc = 0.f;
    for (int i = blockIdx.x * 256 + threadIdx.x; i < n; i += gridDim.x * 256) loc += a[i];
    s[threadIdx.x] = loc;
    __syncthreads();
    for (int off = 128; off; off >>= 1) {
        if (threadIdx.x < off) s[threadIdx.x] += s[threadIdx.x + off];
        __syncthreads();
    }
    if (threadIdx.x == 0) atomicAdd(out, s[0]);
}

__global__ void hist_kernel(const int* __restrict__ ei, int Ne, int Nn,
                            int* __restrict__ counts) {
    int e = blockIdx.x * 256 + threadIdx.x;
    if (e >= Ne + Nn) return;
    int d = (e < Ne) ? ei[Ne + e] : (e - Ne);
    atomicAdd(&counts[d], 1);
}

__global__ void scan_kernel(const int* __restrict__ counts, int* __restrict__ offsets, int n) {
    __shared__ int s[256];
    int tid = threadIdx.x;
    int chunk = (n + 255) / 256;
    int b = tid * chunk;
    int loc = 0;
    for (int j = 0; j < chunk; ++j) { int i = b + j; if (i < n) loc += counts[i]; }
    s[tid] = loc;
    __syncthreads();
    for (int off = 1; off < 256; off <<= 1) {
        int v = (tid >= off) ? s[tid - off] : 0;
        __syncthreads();
        s[tid] += v;
        __syncthreads();
    }
    int run = (tid == 0) ? 0 : s[tid - 1];
    for (int j = 0; j < chunk; ++j) {
        int i = b + j;
        if (i < n) { offsets[i] = run; run += counts[i]; }
    }
    if (tid == 255) offsets[n] = run;
}

__global__ void scatter_kernel(const int* __restrict__ ei, const float* __restrict__ ea,
                               const float* __restrict__ sump, float inv_ne, int Ne, int Nn,
                               int* __restrict__ cursor, int* __restrict__ src_sorted,
                               float* __restrict__ ea_sorted) {
    int e = blockIdx.x * 256 + threadIdx.x;
    if (e >= Ne + Nn) return;
    int s, d; float a;
    if (e < Ne) { s = ei[e]; d = ei[Ne + e]; a = ea[e]; }
    else        { s = e - Ne; d = s; a = sump[0] * inv_ne; }
    int pos = atomicAdd(&cursor[d], 1);
    src_sorted[pos] = s;
    ea_sorted[pos] = a;
}

// ---------------------------------------------------------------------------
// GATv2 fused attention + aggregation, online softmax, edges split across
// the 4 waves. One block per dst node. Each WAVE covers all 512 cols
// (64 lanes x 8 cols; head h = lane>>3 is an 8-lane group -> logit reduce
// is 3 shfl_xor). Wave w processes edges beg+w, beg+w+4, ... with its own
// online-softmax state (defer-max THR=8); states merge exactly through LDS
// at the end via exp(m_w - M) weights. Depth-2 gather prefetch.
// ---------------------------------------------------------------------------
__global__ __launch_bounds__(256) void gat_fused_kernel(
    const f16* __restrict__ xl, const f16* __restrict__ xr,
    const float* __restrict__ we, const float* __restrict__ att,
    const float* __restrict__ bias,
    const int* __restrict__ offsets, const int* __restrict__ src_sorted,
    const float* __restrict__ ea_sorted,
    f16* __restrict__ out, int ldo, int N)
{
    __shared__ float s_acc[8][4][64];   // [k][wave][lane]
    __shared__ float s_m[4][64];
    __shared__ float s_den[4][64];
    const int i = blockIdx.x;
    const int tid = threadIdx.x;
    const int w = tid >> 6, lane = tid & 63;
    const int c8 = lane * 8;

    f16x8 xrv = *(const f16x8*)&xr[(size_t)i * 512 + c8];
    float xr_[8], we_[8], at_[8];
#pragma unroll
    for (int k = 0; k < 8; ++k) xr_[k] = (float)xrv[k];
    *(float4*)&we_[0] = *(const float4*)&we[c8];
    *(float4*)&we_[4] = *(const float4*)&we[c8 + 4];
    *(float4*)&at_[0] = *(const float4*)&att[c8];
    *(float4*)&at_[4] = *(const float4*)&att[c8 + 4];

    const int beg = offsets[i], end = offsets[i + 1];

    float m = -1e30f, den = 0.f;
    float acc[8] = {};

    int e = beg + w;
    float a_c = 0.f, a_n = 0.f;
    f16x8 xv_c = {}, xv_n = {};
    if (e < end) {
        a_c = ea_sorted[e];
        xv_c = *(const f16x8*)&xl[(size_t)src_sorted[e] * 512 + c8];
    }
    if (e + 4 < end) {
        a_n = ea_sorted[e + 4];
        xv_n = *(const f16x8*)&xl[(size_t)src_sorted[e + 4] * 512 + c8];
    }
    for (; e < end; e += 4) {
        float a = a_c; f16x8 xv = xv_c;
        a_c = a_n; xv_c = xv_n;
        if (e + 8 < end) {
            int sn = src_sorted[e + 8];
            a_n = ea_sorted[e + 8];
            xv_n = *(const f16x8*)&xl[(size_t)sn * 512 + c8];
        }
        float x[8];
        float p = 0.f;
#pragma unroll
        for (int k = 0; k < 8; ++k) {
            x[k] = (float)xv[k];
            float v = x[k] + xr_[k] + a * we_[k];
            v = (v > 0.f) ? v : 0.2f * v;
            p = fmaf(v, at_[k], p);
        }
        p += __shfl_xor(p, 1);
        p += __shfl_xor(p, 2);
        p += __shfl_xor(p, 4);
        if (__all(p <= m + 8.f)) {
            float wg = __expf(p - m);
            den += wg;
#pragma unroll
            for (int k = 0; k < 8; ++k) acc[k] = fmaf(wg, x[k], acc[k]);
        } else {
            float mn = fmaxf(m, p);
            float r  = __expf(m - mn);
            float wg = __expf(p - mn);
            den = den * r + wg;
#pragma unroll
            for (int k = 0; k < 8; ++k) acc[k] = fmaf(acc[k], r, wg * x[k]);
            m = mn;
        }
    }

    s_m[w][lane] = m;
    s_den[w][lane] = den;
#pragma unroll
    for (int k = 0; k < 8; ++k) s_acc[k][w][lane] = acc[k];
    __syncthreads();

    const int c2 = tid * 2;
    const int l = c2 >> 3;
    const int k0 = c2 & 7;
    float m0 = s_m[0][l], m1 = s_m[1][l], m2 = s_m[2][l], m3 = s_m[3][l];
    float M = fmaxf(fmaxf(m0, m1), fmaxf(m2, m3));
    float e0 = __expf(m0 - M), e1 = __expf(m1 - M);
    float e2 = __expf(m2 - M), e3 = __expf(m3 - M);
    float D = s_den[0][l] * e0 + s_den[1][l] * e1 + s_den[2][l] * e2 + s_den[3][l] * e3;
    float A0 = s_acc[k0][0][l] * e0 + s_acc[k0][1][l] * e1
             + s_acc[k0][2][l] * e2 + s_acc[k0][3][l] * e3;
    float A1 = s_acc[k0 + 1][0][l] * e0 + s_acc[k0 + 1][1][l] * e1
             + s_acc[k0 + 1][2][l] * e2 + s_acc[k0 + 1][3][l] * e3;
    float rD = 1.f / D;
    float v0 = A0 * rD + bias[c2];
    float v1 = A1 * rD + bias[c2 + 1];
    v0 = (v0 > 0.f) ? v0 : __expf(v0) - 1.f;
    v1 = (v1 > 0.f) ? v1 : __expf(v1) - 1.f;
    f16x2 ov; ov.x = (f16)v0; ov.y = (f16)v1;
    *(f16x2*)&out[(size_t)i * ldo + c2] = ov;
}

// fc2: out[n] = H[n,:512] . w + b (fp32)
__global__ void fc2_kernel(const float* __restrict__ H, const float* __restrict__ w,
                           const float* __restrict__ b, float* __restrict__ out, int N) {
    int wv = threadIdx.x >> 6, lane = threadIdx.x & 63;
    int node = blockIdx.x * 4 + wv;
    if (node >= N) return;
    float s = 0.f;
#pragma unroll
    for (int j = 0; j < 8; ++j)
        s += H[(size_t)node * 512 + j * 64 + lane] * w[j * 64 + lane];
#pragma unroll
    for (int off = 32; off; off >>= 1) s += __shfl_xor(s, off, 64);
    if (lane == 0) out[node] = s + b[0];
}

// ---------------------------------------------------------------------------
extern "C" void kernel_launch(void* const* d_in, const int* in_sizes, int n_in,
                              void* d_out, int out_size, void* d_ws, size_t ws_size,
                              hipStream_t stream) {
    const float* x_seq     = (const float*)d_in[0];
    const int*   edge_index= (const int*)d_in[1];
    const float* edge_attr = (const float*)d_in[2];
    const float* w_ih0 = (const float*)d_in[3];
    const float* w_hh0 = (const float*)d_in[4];
    const float* b_ih0 = (const float*)d_in[5];
    const float* b_hh0 = (const float*)d_in[6];
    const float* w_ih1 = (const float*)d_in[7];
    const float* w_hh1 = (const float*)d_in[8];
    const float* b_ih1 = (const float*)d_in[9];
    const float* b_hh1 = (const float*)d_in[10];
    const float* g0_wl = (const float*)d_in[11];
    const float* g0_bl = (const float*)d_in[12];
    const float* g0_wr = (const float*)d_in[13];
    const float* g0_br = (const float*)d_in[14];
    const float* g0_we = (const float*)d_in[15];
    const float* g0_att= (const float*)d_in[16];
    const float* g0_bias=(const float*)d_in[17];
    const float* g1_wl = (const float*)d_in[18];
    const float* g1_bl = (const float*)d_in[19];
    const float* g1_wr = (const float*)d_in[20];
    const float* g1_br = (const float*)d_in[21];
    const float* g1_we = (const float*)d_in[22];
    const float* g1_att= (const float*)d_in[23];
    const float* g1_bias=(const float*)d_in[24];
    const float* fc1_w = (const float*)d_in[25];
    const float* fc1_b = (const float*)d_in[26];
    const float* fc2_w = (const float*)d_in[27];
    const float* fc2_b = (const float*)d_in[28];
    float* out = (float*)d_out;

    const int Nn = in_sizes[0] / (60 * 16);   // 10000
    const int Ne = in_sizes[1] / 2;           // 320000
    const int Etot = Ne + Nn;
    const int MT = (Nn + 127) / 128;          // 79
    const int Mpad = MT * 128;                // 10112
    const int MTpad8 = ((MT + 7) / 8) * 8;    // 80

    size_t off = 0;
    auto alloc = [&](size_t bytes) -> void* {
        void* r = (char*)d_ws + off;
        off += (bytes + 255) & ~(size_t)255;
        return r;
    };
    f16* W0t   = (f16*)alloc((size_t)1024 * 288 * 2);
    f16* W1t   = (f16*)alloc((size_t)1024 * 512 * 2);
    float* b40 = (float*)alloc(1024 * 4);
    float* b41 = (float*)alloc(1024 * 4);
    f16* Wg0l  = (f16*)alloc((size_t)512 * 256 * 2);
    f16* Wg0r  = (f16*)alloc((size_t)512 * 256 * 2);
    f16* Wg1l  = (f16*)alloc((size_t)512 * 512 * 2);
    f16* Wg1r  = (f16*)alloc((size_t)512 * 512 * 2);
    f16* Wfc1  = (f16*)alloc((size_t)512 * 768 * 2);
    f16* A0b[2]; A0b[0] = (f16*)alloc((size_t)Mpad * 288 * 2);
                 A0b[1] = (f16*)alloc((size_t)Mpad * 288 * 2);
    f16* A1b[2]; A1b[0] = (f16*)alloc((size_t)Mpad * 512 * 2);
                 A1b[1] = (f16*)alloc((size_t)Mpad * 512 * 2);
    float* c0  = (float*)alloc((size_t)Mpad * 256 * 4);
    float* c1  = (float*)alloc((size_t)Mpad * 256 * 4);
    f16* fused = (f16*)alloc((size_t)Mpad * 768 * 2);
    f16* xlbuf = (f16*)alloc((size_t)Mpad * 512 * 2);
    f16* xrbuf = (f16*)alloc((size_t)Mpad * 512 * 2);
    f16* gbuf  = (f16*)alloc((size_t)Mpad * 512 * 2);
    float* hfc1= (float*)alloc((size_t)Mpad * 512 * 4);
    int* counts  = (int*)alloc((size_t)Nn * 4);
    int* offsets = (int*)alloc((size_t)(Nn + 1) * 4);
    int* cursor  = (int*)alloc((size_t)Nn * 4);
    int* src_sorted = (int*)alloc((size_t)Etot * 4);
    float* ea_sorted = (float*)alloc((size_t)Etot * 4);
    float* meanp = (float*)alloc(256);

    // ---- weight / state prep ----
    prep_w0_kernel<<<dim3((1024 * 288 + 255) / 256), 256, 0, stream>>>(w_ih0, w_hh0, W0t);
    prep_w1_kernel<<<dim3((1024 * 512 + 255) / 256), 256, 0, stream>>>(w_ih1, w_hh1, W1t);
    prep_bias4_kernel<<<dim3(4), 256, 0, stream>>>(b_ih0, b_hh0, b40);
    prep_bias4_kernel<<<dim3(4), 256, 0, stream>>>(b_ih1, b_hh1, b41);
    prep_wt_kernel<<<dim3((256 * 512 + 255) / 256), 256, 0, stream>>>(g0_wl, Wg0l, 256, 512);
    prep_wt_kernel<<<dim3((256 * 512 + 255) / 256), 256, 0, stream>>>(g0_wr, Wg0r, 256, 512);
    prep_wt_kernel<<<dim3((512 * 512 + 255) / 256), 256, 0, stream>>>(g1_wl, Wg1l, 512, 512);
    prep_wt_kernel<<<dim3((512 * 512 + 255) / 256), 256, 0, stream>>>(g1_wr, Wg1r, 512, 512);
    prep_wt_kernel<<<dim3((768 * 512 + 255) / 256), 256, 0, stream>>>(fc1_w, Wfc1, 768, 512);
    hipMemsetAsync(A0b[0], 0, (size_t)Mpad * 288 * 2, stream);
    hipMemsetAsync(A0b[1], 0, (size_t)Mpad * 288 * 2, stream);
    hipMemsetAsync(A1b[0], 0, (size_t)Mpad * 512 * 2, stream);
    hipMemsetAsync(A1b[1], 0, (size_t)Mpad * 512 * 2, stream);
    prep_x0_kernel<<<dim3((Nn * 16 + 255) / 256), 256, 0, stream>>>(x_seq, A0b[0], Nn);

    // ---- edge prep (CSR by dst) ----
    hipMemsetAsync(meanp, 0, 4, stream);
    hipMemsetAsync(counts, 0, (size_t)Nn * 4, stream);
    mean_sum_kernel<<<dim3(256), 256, 0, stream>>>(edge_attr, Ne, meanp);
    hist_kernel<<<dim3((Etot + 255) / 256), 256, 0, stream>>>(edge_index, Ne, Nn, counts);
    scan_kernel<<<dim3(1), 256, 0, stream>>>(counts, offsets, Nn);
    hipMemcpyAsync(cursor, offsets, (size_t)Nn * 4, hipMemcpyDeviceToDevice, stream);
    scatter_kernel<<<dim3((Etot + 255) / 256), 256, 0, stream>>>(
        edge_index, edge_attr, meanp, 1.0f / (float)Ne, Ne, Nn, cursor, src_sorted, ea_sorted);

    // ---- 2-layer LSTM, 60 steps ----
    // Preferred: single persistent cooperative kernel (c in registers, no
    // launch-boundary drains). Co-residency verified via occupancy query;
    // any failure falls back to the proven 61-launch sequence.
    int coopDone = 0;
    {
        int occ = 0;
        hipError_t qe = hipOccupancyMaxActiveBlocksPerMultiprocessor(
            &occ, lstm_persist_kernel, 256, 0);
        if (qe == hipSuccess && occ >= 3) {
            int nblk = 768;               // 3 blocks/CU x 256 CUs, >= 1280/2
            f16* A1b0_ = A1b[0]; f16* A1b1_ = A1b[1];
            f16* A0b0_ = A0b[0]; f16* A0b1_ = A0b[1];
            f16* fused_ = fused;
            const float* xs_ = x_seq;
            int M_ = Nn, MT_ = MT, NB_ = nblk;
            const f16* W1t_ = W1t; const float* b41_ = b41;
            const f16* W0t_ = W0t; const float* b40_ = b40;
            void* kargs[] = {
                (void*)&W1t_, (void*)&b41_, (void*)&W0t_, (void*)&b40_,
                (void*)&A1b0_, (void*)&A1b1_, (void*)&A0b0_, (void*)&A0b1_,
                (void*)&fused_, (void*)&xs_, (void*)&M_, (void*)&MT_, (void*)&NB_
            };
            hipError_t le = hipLaunchCooperativeKernel(
                lstm_persist_kernel, dim3(nblk), dim3(256), kargs, 0, stream);
            if (le == hipSuccess) coopDone = 1;
        }
    }
    if (!coopDone) {
        // legacy path: c-state in global memory, 61 launches
        hipMemsetAsync(c0, 0, (size_t)Mpad * 256 * 4, stream);
        hipMemsetAsync(c1, 0, (size_t)Mpad * 256 * 4, stream);
        const int solo_grid = MTpad8 * 8;    // 640
        const int dual_grid = MTpad8 * 16;   // 1280
        lstm_mfma_kernel<<<dim3(solo_grid), 256, 0, stream>>>(
            A0b[0], 288, 288, W0t, b40, c0,
            A1b[0], 512, 0,
            A0b[1], 288, 16,
            x_seq, 1, Nn, MT);
        for (int k = 0; k < 59; ++k) {
            lstm_dual_kernel<<<dim3(dual_grid), 256, 0, stream>>>(
                A1b[k & 1], W1t, b41, c1,
                A1b[(k + 1) & 1], 512, 256,
                A0b[(k + 1) & 1], W0t, b40, c0,
                A1b[(k + 1) & 1], 512, 0,
                A0b[k & 1], 288, 16,
                (k + 1 < 59) ? x_seq : nullptr, k + 2, Nn, MT);
        }
        lstm_mfma_kernel<<<dim3(solo_grid), 256, 0, stream>>>(
            A1b[1], 512, 512, W1t, b41, c1,
            fused, 768, 0,
            nullptr, 0, 0,
            nullptr, 0, Nn, MT);
    }

    // ---- GAT layer 1 (xl/xr in one launch) ----
    gemm16_dual_kernel<<<dim3(MT, 8), 256, 0, stream>>>(
        fused, 768, Wg0l, Wg0r, 256, g0_bl, g0_br, xlbuf, xrbuf, 512, Nn);
    gat_fused_kernel<<<dim3(Nn), 256, 0, stream>>>(
        xlbuf, xrbuf, g0_we, g0_att, g0_bias, offsets, src_sorted, ea_sorted,
        gbuf, 512, Nn);

    // ---- GAT layer 2 (output into fused cols 256..767) ----
    gemm16_dual_kernel<<<dim3(MT, 8), 256, 0, stream>>>(
        gbuf, 512, Wg1l, Wg1r, 512, g1_bl, g1_br, xlbuf, xrbuf, 512, Nn);
    gat_fused_kernel<<<dim3(Nn), 256, 0, stream>>>(
        xlbuf, xrbuf, g1_we, g1_att, g1_bias, offsets, src_sorted, ea_sorted,
        fused + 256, 768, Nn);

    // ---- fusion MLP ----
    gemm16_kernel<<<dim3(MT, 4), 256, 0, stream>>>(
        fused, 768, Wfc1, 768, fc1_b, nullptr, hfc1, 512, 1, Nn);
    fc2_kernel<<<dim3((Nn + 3) / 4), 256, 0, stream>>>(hfc1, fc2_w, fc2_b, out, Nn);
}

// Round 11
// 2801.079 us; speedup vs baseline: 1.0145x; 1.0145x over previous
//
#include <hip/hip_runtime.h>

#define DEV __device__ __forceinline__

typedef _Float16 f16;
typedef _Float16 f16x8 __attribute__((ext_vector_type(8)));
typedef _Float16 f16x2 __attribute__((ext_vector_type(2)));
typedef float f32x4 __attribute__((ext_vector_type(4)));

DEV float sigmoidf_(float x) { return 1.0f / (1.0f + __expf(-x)); }
DEV float tanhf2_(float x)   { return 1.0f - 2.0f / (__expf(2.0f * x) + 1.0f); }

// async global->LDS, 16B per lane. LDS dest = wave-uniform base + lane*16.
DEV void load_lds16(const void* g, void* l) {
    __builtin_amdgcn_global_load_lds(
        (const __attribute__((address_space(1))) char*)(const char*)g,
        (__attribute__((address_space(3))) char*)(unsigned int)(unsigned long long)(char*)l,
        16, 0, 0);
}

// LDS 16x32(f16) tile swizzle: chunk (row,ck) lives at physical slot
// ck ^ (row&3) ^ ((row>>2)&3). Loader permutes the GLOBAL chunk per lane;
// reader picks the matching physical slot (XOR involution).
DEV int swz(int row, int ck) { return ck ^ (row & 3) ^ ((row >> 2) & 3); }

// ---------------------------------------------------------------------------
// LSTM weight prep: Wt[1024][K] fp16, column-order chosen so that in the MFMA
// C-layout the 4 gates of a unit land in one lane's 4 j-fragments.
// dst row rd: T=rd>>7, p=rd&127, wh=(p>>6)&1, j=(p>>4)&3, c=p&15
//   unit u = T*32 + wh*16 + c ; gate g = j ; src row = g*256+u
// W0t: [1024,288] — cols 0..15 x, 16..271 h0, 272..287 zero (pad to K%32==0)
// W1t: [1024,512] — cols 0..255 h0 (wih), 256..511 h1prev (whh)
// ---------------------------------------------------------------------------
__global__ void prep_w0_kernel(const float* __restrict__ wih,
                               const float* __restrict__ whh,
                               f16* __restrict__ dst) {   // [1024,288]
    int idx = blockIdx.x * 256 + threadIdx.x;
    if (idx >= 1024 * 288) return;
    int rd = idx / 288, k = idx - rd * 288;
    int T = rd >> 7, p = rd & 127;
    int u = T * 32 + ((p >> 6) & 1) * 16 + (p & 15);
    int g = (p >> 4) & 3;
    int src = g * 256 + u;
    float v;
    if (k < 16)        v = wih[src * 16 + k];
    else if (k < 272)  v = whh[src * 256 + (k - 16)];
    else               v = 0.f;
    dst[idx] = (f16)v;
}

__global__ void prep_w1_kernel(const float* __restrict__ wih,
                               const float* __restrict__ whh,
                               f16* __restrict__ dst) {   // [1024,512]
    int idx = blockIdx.x * 256 + threadIdx.x;
    if (idx >= 1024 * 512) return;
    int rd = idx >> 9, k = idx & 511;
    int T = rd >> 7, p = rd & 127;
    int u = T * 32 + ((p >> 6) & 1) * 16 + (p & 15);
    int g = (p >> 4) & 3;
    int src = g * 256 + u;
    float v = (k < 256) ? wih[src * 256 + k] : whh[src * 256 + (k - 256)];
    dst[idx] = (f16)v;
}

__global__ void prep_bias4_kernel(const float* __restrict__ bi,
                                  const float* __restrict__ bh,
                                  float* __restrict__ dst) {  // [1024] = [u*4+g]
    int idx = blockIdx.x * 256 + threadIdx.x;
    if (idx >= 1024) return;
    int u = idx >> 2, g = idx & 3;
    dst[idx] = bi[g * 256 + u] + bh[g * 256 + u];
}

// generic [K,N] fp32 -> [N,K] fp16 transpose
__global__ void prep_wt_kernel(const float* __restrict__ src, f16* __restrict__ dst,
                               int K, int N) {
    int idx = blockIdx.x * 256 + threadIdx.x;
    if (idx >= K * N) return;
    int n = idx / K, k = idx - n * K;
    dst[idx] = (f16)src[(size_t)k * N + n];
}

// x_seq[:,0,:16] -> A0buf0 cols 0..15 (lda 288)
__global__ void prep_x0_kernel(const float* __restrict__ x_seq, f16* __restrict__ A0,
                               int Nn) {
    int idx = blockIdx.x * 256 + threadIdx.x;
    if (idx >= Nn * 16) return;
    int m = idx >> 4, f = idx & 15;
    A0[(size_t)m * 288 + f] = (f16)x_seq[(size_t)m * 960 + f];
}

// ---------------------------------------------------------------------------
// Shared MFMA helpers (32-col chunk of a 128x128 tile). Split A-source:
// chunks kc < csw from A (lda), chunks >= csw from A2 (lda2). kc uniform.
// ---------------------------------------------------------------------------
DEV void tile_load_chunk(const f16* __restrict__ A, int lda,
                         const f16* __restrict__ A2, int lda2, int csw,
                         const f16* __restrict__ Bt, int K,
                         int m0, int n0, int kc,
                         f16* __restrict__ sA, f16* __restrict__ sB,
                         int w, int arow, int achk)
{
#pragma unroll
    for (int c = 0; c < 2; ++c) {
        int R = c * 64 + w * 16;
        const f16* ap = (kc < csw)
            ? A  + (size_t)(m0 + R + arow) * lda  + kc * 32 + achk
            : A2 + (size_t)(m0 + R + arow) * lda2 + (kc - csw) * 32 + achk;
        load_lds16(ap, sA + R * 32);
        load_lds16(Bt + (size_t)(n0 + R + arow) * K + kc * 32 + achk, sB + R * 32);
    }
}

DEV void tile_compute_chunk(const f16* __restrict__ sA, const f16* __restrict__ sB,
                            f32x4 (&acc)[4][4], int wr, int wc, int frow, int fsl)
{
    f16x8 af[4], bf[4];
#pragma unroll
    for (int i = 0; i < 4; ++i)
        af[i] = *(const f16x8*)&sA[(wr + i * 16 + frow) * 32 + fsl];
#pragma unroll
    for (int j = 0; j < 4; ++j)
        bf[j] = *(const f16x8*)&sB[(wc + j * 16 + frow) * 32 + fsl];
#pragma unroll
    for (int i = 0; i < 4; ++i)
#pragma unroll
        for (int j = 0; j < 4; ++j)
            acc[i][j] = __builtin_amdgcn_mfma_f32_16x16x32_f16(af[i], bf[j], acc[i][j], 0, 0, 0);
}

// ---------------------------------------------------------------------------
// Tile GEMM core (R4-proven): 128x128 tile, 4 waves 2x2, TRIPLE-buffered
// 32-col chunks with depth-2 prefetch and counted vmcnt:
//   iter kc: s_waitcnt vmcnt(4)  <- chunk kc landed; kc+1 stays in flight
//            s_barrier           <- all waves' writes visible
//            issue chunk kc+2    <- into buf freed at iter kc-1
//            ds_read+MFMA chunk kc
// ---------------------------------------------------------------------------
DEV void gemm_tile_lds(const f16* __restrict__ A, int lda,
                       const f16* __restrict__ A2, int lda2, int csw,
                       const f16* __restrict__ Bt, int K,
                       int m0, int n0,
                       f16* __restrict__ sA, f16* __restrict__ sB,  // [3*4096]
                       f32x4 (&acc)[4][4])
{
    const int tid = threadIdx.x;
    const int w = tid >> 6, lane = tid & 63;
    const int arow = lane >> 2;
    const int achk = swz(arow, lane & 3) * 8;
    const int frow = lane & 15, l4 = lane >> 4;
    const int fsl = swz(frow, l4) * 8;
    const int wr = (w >> 1) * 64, wc = (w & 1) * 64;
    const int nch = K >> 5;

    tile_load_chunk(A, lda, A2, lda2, csw, Bt, K, m0, n0, 0, sA, sB, w, arow, achk);
    if (nch > 1)
        tile_load_chunk(A, lda, A2, lda2, csw, Bt, K, m0, n0, 1,
                        sA + 4096, sB + 4096, w, arow, achk);

    int cb = 0, lb = 2;
    for (int kc = 0; kc < nch; ++kc) {
        if (kc + 1 < nch) asm volatile("s_waitcnt vmcnt(4)" ::: "memory");
        else              asm volatile("s_waitcnt vmcnt(0)" ::: "memory");
        __builtin_amdgcn_s_barrier();
        if (kc + 2 < nch)
            tile_load_chunk(A, lda, A2, lda2, csw, Bt, K, m0, n0, kc + 2,
                            sA + lb * 4096, sB + lb * 4096, w, arow, achk);
        tile_compute_chunk(sA + cb * 4096, sB + cb * 4096, acc, wr, wc, frow, fsl);
        cb = (cb == 2) ? 0 : cb + 1;
        lb = (lb == 2) ? 0 : lb + 1;
    }
}

// ---------------------------------------------------------------------------
// LSTM step core (f16 MFMA): gates = A @ Wt^T (+bias), cell update.
// h written ONCE (hA). x_{tnext} staged into xdst (lda 288, cols 0..15).
// c-state prefetched before the K-loop. bx/by from XCD-swizzled id.
// ---------------------------------------------------------------------------
DEV void lstm_step_core(
    f16* __restrict__ sA, f16* __restrict__ sB,   // each [3*4096] f16
    int bx, int by,
    const f16* __restrict__ A, int lda,
    const f16* __restrict__ A2, int lda2, int csw, int K,
    const f16* __restrict__ Wt,
    const float* __restrict__ bias4,
    float* __restrict__ c_state,
    f16* __restrict__ hA, int ldhA, int offhA,
    f16* __restrict__ xdst, const float* __restrict__ xsrc, int tnext,
    int M)
{
    const int tid = threadIdx.x;
    const int w = tid >> 6, lane = tid & 63;
    const int m0 = bx * 128, n0 = by * 128;
    const int wr = (w >> 1) * 64;

    // prefetch c-state (epilogue inputs) — K-loop covers the latency.
    const int u = by * 32 + (w & 1) * 16 + (lane & 15);
    const int rbase = m0 + wr + (lane >> 4) * 4;
    float cold[4][4];
#pragma unroll
    for (int i = 0; i < 4; ++i)
#pragma unroll
        for (int r = 0; r < 4; ++r)
            cold[i][r] = c_state[(size_t)(rbase + i * 16 + r) * 256 + u];

    f32x4 acc[4][4] = {};
    gemm_tile_lds(A, lda, A2, lda2, csw, Wt, K, m0, n0, sA, sB, acc);

    // epilogue: lane owns unit u, acc[i][j][r] = gate j of row m
    const float4 bb = *(const float4*)&bias4[u * 4];
#pragma unroll
    for (int i = 0; i < 4; ++i) {
#pragma unroll
        for (int r = 0; r < 4; ++r) {
            int m = rbase + i * 16 + r;
            if (m < M) {
                float gi = sigmoidf_(acc[i][0][r] + bb.x);
                float gf = sigmoidf_(acc[i][1][r] + bb.y);
                float gg = tanhf2_(acc[i][2][r] + bb.z);
                float go = sigmoidf_(acc[i][3][r] + bb.w);
                float cn = gf * cold[i][r] + gi * gg;
                c_state[(size_t)m * 256 + u] = cn;
                hA[(size_t)m * ldhA + offhA + u] = (f16)(go * tanhf2_(cn));
            }
        }
    }
    // layer0 blocks (by==0) stage x_{tnext} into xdst cols 0..15 (lda 288)
    if (xsrc && by == 0) {
        int row = tid >> 1, fb = (tid & 1) * 8;
        int m = m0 + row;
        if (m < M) {
            const float* xp = xsrc + (size_t)m * 960 + tnext * 16 + fb;
            f16* dp = xdst + (size_t)m * 288 + fb;
#pragma unroll
            for (int q = 0; q < 8; ++q) dp[q] = (f16)xp[q];
        }
    }
}

// solo (single-layer) LSTM step. Grid: mtPad8*8 linear, XCD-swizzled:
// l%8 = x%8 -> all 8 y-blocks of one x-tile land on one XCD (A/c L2 locality).
__global__ __launch_bounds__(256) void lstm_mfma_kernel(
    const f16* __restrict__ A, int lda,
    const f16* __restrict__ A2, int lda2, int csw, int K,
    const f16* __restrict__ Wt, const float* __restrict__ bias4,
    float* __restrict__ c_state,
    f16* __restrict__ hA, int ldhA, int offhA,
    f16* __restrict__ xdst, const float* __restrict__ xsrc, int tnext,
    int M, int mtiles)
{
    __shared__ __align__(16) f16 sA[3 * 4096];
    __shared__ __align__(16) f16 sB[3 * 4096];
    const int l = blockIdx.x;
    const int xcd = l & 7, q = l >> 3;
    const int y = q & 7, xhi = q >> 3;
    const int x = xhi * 8 + xcd;
    if (x >= mtiles) return;
    lstm_step_core(sA, sB, x, y, A, lda, A2, lda2, csw, K, Wt, bias4, c_state,
                   hA, ldhA, offhA, xdst, xsrc, tnext, M);
}

// merged: z=0 -> layer1(k), z=1 -> layer0(k+1). All 16 (y,z) blocks of one
// x-tile share an XCD. h0 lives ONLY in A0b (cols 16..271); h1 in the slim
// 256-wide A1S buffers. L1 reads h0 via the split-A loader (csw=8):
//   chunks 0..7  <- A0cur+16 (lda 288)  = h0(k)
//   chunks 8..15 <- A1Scur   (lda 256)  = h1(k-1)
__global__ __launch_bounds__(256) void lstm_dual_kernel(
    const f16* __restrict__ A0cur,   // A0b[(k+1)&1]: [x(k+1)|h0(k)|pad]
    f16* __restrict__ A0nxt,         // A0b[k&1]: gets h0(k+1)+x(k+2)
    const f16* __restrict__ A1Scur,  // A1S[k&1]: h1(k-1)
    f16* __restrict__ A1Snxt,        // A1S[(k+1)&1]: gets h1(k)
    const f16* __restrict__ W1t, const float* __restrict__ b41,
    float* __restrict__ c1,
    const f16* __restrict__ W0t, const float* __restrict__ b40,
    float* __restrict__ c0,
    const float* __restrict__ xsrc, int tnext, int M, int mtiles)
{
    __shared__ __align__(16) f16 sA[3 * 4096];
    __shared__ __align__(16) f16 sB[3 * 4096];
    const int l = blockIdx.x;
    const int xcd = l & 7, q = l >> 3;
    const int yz = q & 15, xhi = q >> 4;
    const int x = xhi * 8 + xcd;
    if (x >= mtiles) return;
    const int y = yz & 7, z = yz >> 3;
    if (z == 0)
        lstm_step_core(sA, sB, x, y, A0cur + 16, 288, A1Scur, 256, 8, 512,
                       W1t, b41, c1, A1Snxt, 256, 0,
                       nullptr, nullptr, 0, M);
    else
        lstm_step_core(sA, sB, x, y, A0cur, 288, A0cur, 288, 1 << 30, 288,
                       W0t, b40, c0, A0nxt, 288, 16,
                       A0nxt, xsrc, tnext, M);
}

// ---------------------------------------------------------------------------
// Generic f16 MFMA GEMM (triple-buffered): C = act(A @ Bt^T + bias)
// ---------------------------------------------------------------------------
__global__ __launch_bounds__(256) void gemm16_kernel(
    const f16* __restrict__ A, int lda,
    const f16* __restrict__ Bt, int K,
    const float* __restrict__ bias,
    f16* __restrict__ C16, float* __restrict__ C32, int ldc,
    int act, int M)
{
    __shared__ __align__(16) f16 sA[3 * 4096];
    __shared__ __align__(16) f16 sB[3 * 4096];
    const int tid = threadIdx.x;
    const int w = tid >> 6, lane = tid & 63;
    const int m0 = blockIdx.x * 128, n0 = blockIdx.y * 128;
    const int wr = (w >> 1) * 64, wcn = (w & 1) * 64;

    f32x4 acc[4][4] = {};
    gemm_tile_lds(A, lda, A, lda, 1 << 30, Bt, K, m0, n0, sA, sB, acc);

    const int rbase = m0 + wr + (lane >> 4) * 4;
#pragma unroll
    for (int i = 0; i < 4; ++i) {
#pragma unroll
        for (int r = 0; r < 4; ++r) {
            int m = rbase + i * 16 + r;
            if (m >= M) continue;
#pragma unroll
            for (int j = 0; j < 4; ++j) {
                int n = n0 + wcn + j * 16 + (lane & 15);
                float v = acc[i][j][r] + bias[n];
                if (act == 1) v = fmaxf(v, 0.f);
                if (C16) C16[(size_t)m * ldc + n] = (f16)v;
                else     C32[(size_t)m * ldc + n] = v;
            }
        }
    }
}

// dual-B variant: y<4 -> (Btl,biasl,Cl), y>=4 -> (Btr,biasr,Cr). fp16 out.
__global__ __launch_bounds__(256) void gemm16_dual_kernel(
    const f16* __restrict__ A, int lda,
    const f16* __restrict__ Btl, const f16* __restrict__ Btr, int K,
    const float* __restrict__ biasl, const float* __restrict__ biasr,
    f16* __restrict__ Cl, f16* __restrict__ Cr, int ldc, int M)
{
    __shared__ __align__(16) f16 sA[3 * 4096];
    __shared__ __align__(16) f16 sB[3 * 4096];
    const int side = blockIdx.y >> 2;
    const f16* Bt = side ? Btr : Btl;
    const float* bias = side ? biasr : biasl;
    f16* C16 = side ? Cr : Cl;
    const int tid = threadIdx.x;
    const int w = tid >> 6, lane = tid & 63;
    const int m0 = blockIdx.x * 128, n0 = (blockIdx.y & 3) * 128;
    const int wr = (w >> 1) * 64, wcn = (w & 1) * 64;

    f32x4 acc[4][4] = {};
    gemm_tile_lds(A, lda, A, lda, 1 << 30, Bt, K, m0, n0, sA, sB, acc);

    const int rbase = m0 + wr + (lane >> 4) * 4;
#pragma unroll
    for (int i = 0; i < 4; ++i) {
#pragma unroll
        for (int r = 0; r < 4; ++r) {
            int m = rbase + i * 16 + r;
            if (m >= M) continue;
#pragma unroll
            for (int j = 0; j < 4; ++j) {
                int n = n0 + wcn + j * 16 + (lane & 15);
                float v = acc[i][j][r] + bias[n];
                C16[(size_t)m * ldc + n] = (f16)v;
            }
        }
    }
}

// ---------------------------------------------------------------------------
// Edge preprocessing
// ---------------------------------------------------------------------------
__global__ void mean_sum_kernel(const float* __restrict__ a, int n, float* __restrict__ out) {
    __shared__ float s[256];
    float loc = 0.f;
    for (int i = blockIdx.x * 256 + threadIdx.x; i < n; i += gridDim.x * 256) loc += a[i];
    s[threadIdx.x] = loc;
    __syncthreads();
    for (int off = 128; off; off >>= 1) {
        if (threadIdx.x < off) s[threadIdx.x] += s[threadIdx.x + off];
        __syncthreads();
    }
    if (threadIdx.x == 0) atomicAdd(out, s[0]);
}

__global__ void hist_kernel(const int* __restrict__ ei, int Ne, int Nn,
                            int* __restrict__ counts) {
    int e = blockIdx.x * 256 + threadIdx.x;
    if (e >= Ne + Nn) return;
    int d = (e < Ne) ? ei[Ne + e] : (e - Ne);
    atomicAdd(&counts[d], 1);
}

__global__ void scan_kernel(const int* __restrict__ counts, int* __restrict__ offsets, int n) {
    __shared__ int s[256];
    int tid = threadIdx.x;
    int chunk = (n + 255) / 256;
    int b = tid * chunk;
    int loc = 0;
    for (int j = 0; j < chunk; ++j) { int i = b + j; if (i < n) loc += counts[i]; }
    s[tid] = loc;
    __syncthreads();
    for (int off = 1; off < 256; off <<= 1) {
        int v = (tid >= off) ? s[tid - off] : 0;
        __syncthreads();
        s[tid] += v;
        __syncthreads();
    }
    int run = (tid == 0) ? 0 : s[tid - 1];
    for (int j = 0; j < chunk; ++j) {
        int i = b + j;
        if (i < n) { offsets[i] = run; run += counts[i]; }
    }
    if (tid == 255) offsets[n] = run;
}

__global__ void scatter_kernel(const int* __restrict__ ei, const float* __restrict__ ea,
                               const float* __restrict__ sump, float inv_ne, int Ne, int Nn,
                               int* __restrict__ cursor, int* __restrict__ src_sorted,
                               float* __restrict__ ea_sorted) {
    int e = blockIdx.x * 256 + threadIdx.x;
    if (e >= Ne + Nn) return;
    int s, d; float a;
    if (e < Ne) { s = ei[e]; d = ei[Ne + e]; a = ea[e]; }
    else        { s = e - Ne; d = s; a = sump[0] * inv_ne; }
    int pos = atomicAdd(&cursor[d], 1);
    src_sorted[pos] = s;
    ea_sorted[pos] = a;
}

// ---------------------------------------------------------------------------
// GATv2 fused attention + aggregation, online softmax, edges split across
// the 4 waves. One block per dst node. Each WAVE covers all 512 cols
// (64 lanes x 8 cols; head h = lane>>3 is an 8-lane group -> logit reduce
// is 3 shfl_xor). Wave w processes edges beg+w, beg+w+4, ... with its own
// online-softmax state (defer-max THR=8); states merge exactly through LDS
// at the end via exp(m_w - M) weights. Depth-2 gather prefetch.
// ---------------------------------------------------------------------------
__global__ __launch_bounds__(256) void gat_fused_kernel(
    const f16* __restrict__ xl, const f16* __restrict__ xr,
    const float* __restrict__ we, const float* __restrict__ att,
    const float* __restrict__ bias,
    const int* __restrict__ offsets, const int* __restrict__ src_sorted,
    const float* __restrict__ ea_sorted,
    f16* __restrict__ out, int ldo, int N)
{
    __shared__ float s_acc[8][4][64];   // [k][wave][lane]
    __shared__ float s_m[4][64];
    __shared__ float s_den[4][64];
    const int i = blockIdx.x;
    const int tid = threadIdx.x;
    const int w = tid >> 6, lane = tid & 63;
    const int c8 = lane * 8;

    f16x8 xrv = *(const f16x8*)&xr[(size_t)i * 512 + c8];
    float xr_[8], we_[8], at_[8];
#pragma unroll
    for (int k = 0; k < 8; ++k) xr_[k] = (float)xrv[k];
    *(float4*)&we_[0] = *(const float4*)&we[c8];
    *(float4*)&we_[4] = *(const float4*)&we[c8 + 4];
    *(float4*)&at_[0] = *(const float4*)&att[c8];
    *(float4*)&at_[4] = *(const float4*)&att[c8 + 4];

    const int beg = offsets[i], end = offsets[i + 1];

    float m = -1e30f, den = 0.f;
    float acc[8] = {};

    int e = beg + w;
    float a_c = 0.f, a_n = 0.f;
    f16x8 xv_c = {}, xv_n = {};
    if (e < end) {
        a_c = ea_sorted[e];
        xv_c = *(const f16x8*)&xl[(size_t)src_sorted[e] * 512 + c8];
    }
    if (e + 4 < end) {
        a_n = ea_sorted[e + 4];
        xv_n = *(const f16x8*)&xl[(size_t)src_sorted[e + 4] * 512 + c8];
    }
    for (; e < end; e += 4) {
        float a = a_c; f16x8 xv = xv_c;
        a_c = a_n; xv_c = xv_n;
        if (e + 8 < end) {
            int sn = src_sorted[e + 8];
            a_n = ea_sorted[e + 8];
            xv_n = *(const f16x8*)&xl[(size_t)sn * 512 + c8];
        }
        float x[8];
        float p = 0.f;
#pragma unroll
        for (int k = 0; k < 8; ++k) {
            x[k] = (float)xv[k];
            float v = x[k] + xr_[k] + a * we_[k];
            v = (v > 0.f) ? v : 0.2f * v;
            p = fmaf(v, at_[k], p);
        }
        p += __shfl_xor(p, 1);
        p += __shfl_xor(p, 2);
        p += __shfl_xor(p, 4);
        if (__all(p <= m + 8.f)) {
            float wg = __expf(p - m);
            den += wg;
#pragma unroll
            for (int k = 0; k < 8; ++k) acc[k] = fmaf(wg, x[k], acc[k]);
        } else {
            float mn = fmaxf(m, p);
            float r  = __expf(m - mn);
            float wg = __expf(p - mn);
            den = den * r + wg;
#pragma unroll
            for (int k = 0; k < 8; ++k) acc[k] = fmaf(acc[k], r, wg * x[k]);
            m = mn;
        }
    }

    s_m[w][lane] = m;
    s_den[w][lane] = den;
#pragma unroll
    for (int k = 0; k < 8; ++k) s_acc[k][w][lane] = acc[k];
    __syncthreads();

    const int c2 = tid * 2;
    const int l = c2 >> 3;
    const int k0 = c2 & 7;
    float m0 = s_m[0][l], m1 = s_m[1][l], m2 = s_m[2][l], m3 = s_m[3][l];
    float M = fmaxf(fmaxf(m0, m1), fmaxf(m2, m3));
    float e0 = __expf(m0 - M), e1 = __expf(m1 - M);
    float e2 = __expf(m2 - M), e3 = __expf(m3 - M);
    float D = s_den[0][l] * e0 + s_den[1][l] * e1 + s_den[2][l] * e2 + s_den[3][l] * e3;
    float A0 = s_acc[k0][0][l] * e0 + s_acc[k0][1][l] * e1
             + s_acc[k0][2][l] * e2 + s_acc[k0][3][l] * e3;
    float A1 = s_acc[k0 + 1][0][l] * e0 + s_acc[k0 + 1][1][l] * e1
             + s_acc[k0 + 1][2][l] * e2 + s_acc[k0 + 1][3][l] * e3;
    float rD = 1.f / D;
    float v0 = A0 * rD + bias[c2];
    float v1 = A1 * rD + bias[c2 + 1];
    v0 = (v0 > 0.f) ? v0 : __expf(v0) - 1.f;
    v1 = (v1 > 0.f) ? v1 : __expf(v1) - 1.f;
    f16x2 ov; ov.x = (f16)v0; ov.y = (f16)v1;
    *(f16x2*)&out[(size_t)i * ldo + c2] = ov;
}

// fc2: out[n] = H[n,:512] . w + b (fp32)
__global__ void fc2_kernel(const float* __restrict__ H, const float* __restrict__ w,
                           const float* __restrict__ b, float* __restrict__ out, int N) {
    int wv = threadIdx.x >> 6, lane = threadIdx.x & 63;
    int node = blockIdx.x * 4 + wv;
    if (node >= N) return;
    float s = 0.f;
#pragma unroll
    for (int j = 0; j < 8; ++j)
        s += H[(size_t)node * 512 + j * 64 + lane] * w[j * 64 + lane];
#pragma unroll
    for (int off = 32; off; off >>= 1) s += __shfl_xor(s, off, 64);
    if (lane == 0) out[node] = s + b[0];
}

// ---------------------------------------------------------------------------
extern "C" void kernel_launch(void* const* d_in, const int* in_sizes, int n_in,
                              void* d_out, int out_size, void* d_ws, size_t ws_size,
                              hipStream_t stream) {
    const float* x_seq     = (const float*)d_in[0];
    const int*   edge_index= (const int*)d_in[1];
    const float* edge_attr = (const float*)d_in[2];
    const float* w_ih0 = (const float*)d_in[3];
    const float* w_hh0 = (const float*)d_in[4];
    const float* b_ih0 = (const float*)d_in[5];
    const float* b_hh0 = (const float*)d_in[6];
    const float* w_ih1 = (const float*)d_in[7];
    const float* w_hh1 = (const float*)d_in[8];
    const float* b_ih1 = (const float*)d_in[9];
    const float* b_hh1 = (const float*)d_in[10];
    const float* g0_wl = (const float*)d_in[11];
    const float* g0_bl = (const float*)d_in[12];
    const float* g0_wr = (const float*)d_in[13];
    const float* g0_br = (const float*)d_in[14];
    const float* g0_we = (const float*)d_in[15];
    const float* g0_att= (const float*)d_in[16];
    const float* g0_bias=(const float*)d_in[17];
    const float* g1_wl = (const float*)d_in[18];
    const float* g1_bl = (const float*)d_in[19];
    const float* g1_wr = (const float*)d_in[20];
    const float* g1_br = (const float*)d_in[21];
    const float* g1_we = (const float*)d_in[22];
    const float* g1_att= (const float*)d_in[23];
    const float* g1_bias=(const float*)d_in[24];
    const float* fc1_w = (const float*)d_in[25];
    const float* fc1_b = (const float*)d_in[26];
    const float* fc2_w = (const float*)d_in[27];
    const float* fc2_b = (const float*)d_in[28];
    float* out = (float*)d_out;

    const int Nn = in_sizes[0] / (60 * 16);   // 10000
    const int Ne = in_sizes[1] / 2;           // 320000
    const int Etot = Ne + Nn;
    const int MT = (Nn + 127) / 128;          // 79
    const int Mpad = MT * 128;                // 10112
    const int MTpad8 = ((MT + 7) / 8) * 8;    // 80

    size_t off = 0;
    auto alloc = [&](size_t bytes) -> void* {
        void* r = (char*)d_ws + off;
        off += (bytes + 255) & ~(size_t)255;
        return r;
    };
    f16* W0t   = (f16*)alloc((size_t)1024 * 288 * 2);
    f16* W1t   = (f16*)alloc((size_t)1024 * 512 * 2);
    float* b40 = (float*)alloc(1024 * 4);
    float* b41 = (float*)alloc(1024 * 4);
    f16* Wg0l  = (f16*)alloc((size_t)512 * 256 * 2);
    f16* Wg0r  = (f16*)alloc((size_t)512 * 256 * 2);
    f16* Wg1l  = (f16*)alloc((size_t)512 * 512 * 2);
    f16* Wg1r  = (f16*)alloc((size_t)512 * 512 * 2);
    f16* Wfc1  = (f16*)alloc((size_t)512 * 768 * 2);
    f16* A0b[2]; A0b[0] = (f16*)alloc((size_t)Mpad * 288 * 2);
                 A0b[1] = (f16*)alloc((size_t)Mpad * 288 * 2);
    f16* A1S[2]; A1S[0] = (f16*)alloc((size_t)Mpad * 256 * 2);
                 A1S[1] = (f16*)alloc((size_t)Mpad * 256 * 2);
    float* c0  = (float*)alloc((size_t)Mpad * 256 * 4);
    float* c1  = (float*)alloc((size_t)Mpad * 256 * 4);
    f16* fused = (f16*)alloc((size_t)Mpad * 768 * 2);
    f16* xlbuf = (f16*)alloc((size_t)Mpad * 512 * 2);
    f16* xrbuf = (f16*)alloc((size_t)Mpad * 512 * 2);
    f16* gbuf  = (f16*)alloc((size_t)Mpad * 512 * 2);
    float* hfc1= (float*)alloc((size_t)Mpad * 512 * 4);
    int* counts  = (int*)alloc((size_t)Nn * 4);
    int* offsets = (int*)alloc((size_t)(Nn + 1) * 4);
    int* cursor  = (int*)alloc((size_t)Nn * 4);
    int* src_sorted = (int*)alloc((size_t)Etot * 4);
    float* ea_sorted = (float*)alloc((size_t)Etot * 4);
    float* meanp = (float*)alloc(256);

    // ---- weight / state prep ----
    prep_w0_kernel<<<dim3((1024 * 288 + 255) / 256), 256, 0, stream>>>(w_ih0, w_hh0, W0t);
    prep_w1_kernel<<<dim3((1024 * 512 + 255) / 256), 256, 0, stream>>>(w_ih1, w_hh1, W1t);
    prep_bias4_kernel<<<dim3(4), 256, 0, stream>>>(b_ih0, b_hh0, b40);
    prep_bias4_kernel<<<dim3(4), 256, 0, stream>>>(b_ih1, b_hh1, b41);
    prep_wt_kernel<<<dim3((256 * 512 + 255) / 256), 256, 0, stream>>>(g0_wl, Wg0l, 256, 512);
    prep_wt_kernel<<<dim3((256 * 512 + 255) / 256), 256, 0, stream>>>(g0_wr, Wg0r, 256, 512);
    prep_wt_kernel<<<dim3((512 * 512 + 255) / 256), 256, 0, stream>>>(g1_wl, Wg1l, 512, 512);
    prep_wt_kernel<<<dim3((512 * 512 + 255) / 256), 256, 0, stream>>>(g1_wr, Wg1r, 512, 512);
    prep_wt_kernel<<<dim3((768 * 512 + 255) / 256), 256, 0, stream>>>(fc1_w, Wfc1, 768, 512);
    hipMemsetAsync(A0b[0], 0, (size_t)Mpad * 288 * 2, stream);
    hipMemsetAsync(A0b[1], 0, (size_t)Mpad * 288 * 2, stream);
    hipMemsetAsync(A1S[0], 0, (size_t)Mpad * 256 * 2, stream);
    hipMemsetAsync(A1S[1], 0, (size_t)Mpad * 256 * 2, stream);
    hipMemsetAsync(c0, 0, (size_t)Mpad * 256 * 4, stream);
    hipMemsetAsync(c1, 0, (size_t)Mpad * 256 * 4, stream);
    prep_x0_kernel<<<dim3((Nn * 16 + 255) / 256), 256, 0, stream>>>(x_seq, A0b[0], Nn);

    // ---- edge prep (CSR by dst) ----
    hipMemsetAsync(meanp, 0, 4, stream);
    hipMemsetAsync(counts, 0, (size_t)Nn * 4, stream);
    mean_sum_kernel<<<dim3(256), 256, 0, stream>>>(edge_attr, Ne, meanp);
    hist_kernel<<<dim3((Etot + 255) / 256), 256, 0, stream>>>(edge_index, Ne, Nn, counts);
    scan_kernel<<<dim3(1), 256, 0, stream>>>(counts, offsets, Nn);
    hipMemcpyAsync(cursor, offsets, (size_t)Nn * 4, hipMemcpyDeviceToDevice, stream);
    scatter_kernel<<<dim3((Etot + 255) / 256), 256, 0, stream>>>(
        edge_index, edge_attr, meanp, 1.0f / (float)Ne, Ne, Nn, cursor, src_sorted, ea_sorted);

    // ---- 2-layer LSTM, 60 steps; L1(k) and L0(k+1) co-scheduled ----
    const int solo_grid = MTpad8 * 8;    // 640
    const int dual_grid = MTpad8 * 16;   // 1280
    // L0(0): A = A0b[0] (x(0)|h0(-1)=0); h0(0) -> A0b[1] cols 16..271;
    // stage x(1) into A0b[1] cols 0..15.
    lstm_mfma_kernel<<<dim3(solo_grid), 256, 0, stream>>>(
        A0b[0], 288, A0b[0], 288, 1 << 30, 288,
        W0t, b40, c0,
        A0b[1], 288, 16,
        A0b[1], x_seq, 1, Nn, MT);
    // merged L1(k) + L0(k+1), k = 0..58
    for (int k = 0; k < 59; ++k) {
        lstm_dual_kernel<<<dim3(dual_grid), 256, 0, stream>>>(
            A0b[(k + 1) & 1], A0b[k & 1],
            A1S[k & 1], A1S[(k + 1) & 1],
            W1t, b41, c1,
            W0t, b40, c0,
            (k + 1 < 59) ? x_seq : nullptr, k + 2, Nn, MT);
    }
    // L1(59): h0(59) in A0b[0] cols 16..271 (written at dual k=58),
    // h1(58) in A1S[1]; write h1_59 (node) into fused cols 0..255.
    lstm_mfma_kernel<<<dim3(solo_grid), 256, 0, stream>>>(
        A0b[0] + 16, 288, A1S[1], 256, 8, 512,
        W1t, b41, c1,
        fused, 768, 0,
        nullptr, nullptr, 0, Nn, MT);

    // ---- GAT layer 1 (xl/xr in one launch) ----
    gemm16_dual_kernel<<<dim3(MT, 8), 256, 0, stream>>>(
        fused, 768, Wg0l, Wg0r, 256, g0_bl, g0_br, xlbuf, xrbuf, 512, Nn);
    gat_fused_kernel<<<dim3(Nn), 256, 0, stream>>>(
        xlbuf, xrbuf, g0_we, g0_att, g0_bias, offsets, src_sorted, ea_sorted,
        gbuf, 512, Nn);

    // ---- GAT layer 2 (output into fused cols 256..767) ----
    gemm16_dual_kernel<<<dim3(MT, 8), 256, 0, stream>>>(
        gbuf, 512, Wg1l, Wg1r, 512, g1_bl, g1_br, xlbuf, xrbuf, 512, Nn);
    gat_fused_kernel<<<dim3(Nn), 256, 0, stream>>>(
        xlbuf, xrbuf, g1_we, g1_att, g1_bias, offsets, src_sorted, ea_sorted,
        fused + 256, 768, Nn);

    // ---- fusion MLP ----
    gemm16_kernel<<<dim3(MT, 4), 256, 0, stream>>>(
        fused, 768, Wfc1, 768, fc1_b, nullptr, hfc1, 512, 1, Nn);
    fc2_kernel<<<dim3((Nn + 3) / 4), 256, 0, stream>>>(hfc1, fc2_w, fc2_b, out, Nn);
}

// Round 12
// 2701.080 us; speedup vs baseline: 1.0520x; 1.0370x over previous
//
#include <hip/hip_runtime.h>

#define DEV __device__ __forceinline__

typedef _Float16 f16;
typedef _Float16 f16x8 __attribute__((ext_vector_type(8)));
typedef _Float16 f16x2 __attribute__((ext_vector_type(2)));
typedef float f32x4 __attribute__((ext_vector_type(4)));

DEV float sigmoidf_(float x) { return 1.0f / (1.0f + __expf(-x)); }
DEV float tanhf2_(float x)   { return 1.0f - 2.0f / (__expf(2.0f * x) + 1.0f); }

// async global->LDS, 16B per lane. LDS dest = wave-uniform base + lane*16.
DEV void load_lds16(const void* g, void* l) {
    __builtin_amdgcn_global_load_lds(
        (const __attribute__((address_space(1))) char*)(const char*)g,
        (__attribute__((address_space(3))) char*)(unsigned int)(unsigned long long)(char*)l,
        16, 0, 0);
}

// LDS 16x32(f16) tile swizzle: chunk (row,ck) lives at physical slot
// ck ^ (row&3) ^ ((row>>2)&3). Loader permutes the GLOBAL chunk per lane;
// reader picks the matching physical slot (XOR involution).
DEV int swz(int row, int ck) { return ck ^ (row & 3) ^ ((row >> 2) & 3); }

// ---------------------------------------------------------------------------
// LSTM weight prep: Wt[1024][K] fp16, column-order chosen so that in the MFMA
// C-layout the 4 gates of a unit land in one lane's 4 j-fragments.
// dst row rd: T=rd>>7, p=rd&127, wh=(p>>6)&1, j=(p>>4)&3, c=p&15
//   unit u = T*32 + wh*16 + c ; gate g = j ; src row = g*256+u
// W0t: [1024,288] — cols 0..15 x, 16..271 h0, 272..287 zero (pad to K%32==0)
// ---------------------------------------------------------------------------
__global__ void prep_w0_kernel(const float* __restrict__ wih,
                               const float* __restrict__ whh,
                               f16* __restrict__ dst) {   // [1024,288]
    int idx = blockIdx.x * 256 + threadIdx.x;
    if (idx >= 1024 * 288) return;
    int rd = idx / 288, k = idx - rd * 288;
    int T = rd >> 7, p = rd & 127;
    int u = T * 32 + ((p >> 6) & 1) * 16 + (p & 15);
    int g = (p >> 4) & 3;
    int src = g * 256 + u;
    float v;
    if (k < 16)        v = wih[src * 16 + k];
    else if (k < 272)  v = whh[src * 256 + (k - 16)];
    else               v = 0.f;
    dst[idx] = (f16)v;
}

__global__ void prep_w1_kernel(const float* __restrict__ wih,
                               const float* __restrict__ whh,
                               f16* __restrict__ dst) {   // [1024,512]
    int idx = blockIdx.x * 256 + threadIdx.x;
    if (idx >= 1024 * 512) return;
    int rd = idx >> 9, k = idx & 511;
    int T = rd >> 7, p = rd & 127;
    int u = T * 32 + ((p >> 6) & 1) * 16 + (p & 15);
    int g = (p >> 4) & 3;
    int src = g * 256 + u;
    float v = (k < 256) ? wih[src * 256 + k] : whh[src * 256 + (k - 256)];
    dst[idx] = (f16)v;
}

__global__ void prep_bias4_kernel(const float* __restrict__ bi,
                                  const float* __restrict__ bh,
                                  float* __restrict__ dst) {  // [1024] = [u*4+g]
    int idx = blockIdx.x * 256 + threadIdx.x;
    if (idx >= 1024) return;
    int u = idx >> 2, g = idx & 3;
    dst[idx] = bi[g * 256 + u] + bh[g * 256 + u];
}

// generic [K,N] fp32 -> [N,K] fp16 transpose
__global__ void prep_wt_kernel(const float* __restrict__ src, f16* __restrict__ dst,
                               int K, int N) {
    int idx = blockIdx.x * 256 + threadIdx.x;
    if (idx >= K * N) return;
    int n = idx / K, k = idx - n * K;
    dst[idx] = (f16)src[(size_t)k * N + n];
}

// x_seq[:,0,:16] -> A0buf0 cols 0..15 (lda 288)
__global__ void prep_x0_kernel(const float* __restrict__ x_seq, f16* __restrict__ A0,
                               int Nn) {
    int idx = blockIdx.x * 256 + threadIdx.x;
    if (idx >= Nn * 16) return;
    int m = idx >> 4, f = idx & 15;
    A0[(size_t)m * 288 + f] = (f16)x_seq[(size_t)m * 960 + f];
}

// out[n] = fc2_b (accumulated into by the fused fc1+fc2 GEMM)
__global__ void out_init_kernel(float* __restrict__ out, const float* __restrict__ b,
                                int Nn) {
    int idx = blockIdx.x * 256 + threadIdx.x;
    if (idx < Nn) out[idx] = b[0];
}

// ---------------------------------------------------------------------------
// Shared MFMA helpers (32-col chunk of a 128x128 tile)
// ---------------------------------------------------------------------------
DEV void tile_load_chunk(const f16* __restrict__ A, int lda,
                         const f16* __restrict__ Bt, int K,
                         int m0, int n0, int k0,
                         f16* __restrict__ sA, f16* __restrict__ sB,
                         int w, int arow, int achk)
{
#pragma unroll
    for (int c = 0; c < 2; ++c) {
        int R = c * 64 + w * 16;
        load_lds16(A + (size_t)(m0 + R + arow) * lda + k0 + achk, sA + R * 32);
        load_lds16(Bt + (size_t)(n0 + R + arow) * K + k0 + achk, sB + R * 32);
    }
}

DEV void tile_compute_chunk(const f16* __restrict__ sA, const f16* __restrict__ sB,
                            f32x4 (&acc)[4][4], int wr, int wc, int frow, int fsl)
{
    f16x8 af[4], bf[4];
#pragma unroll
    for (int i = 0; i < 4; ++i)
        af[i] = *(const f16x8*)&sA[(wr + i * 16 + frow) * 32 + fsl];
#pragma unroll
    for (int j = 0; j < 4; ++j)
        bf[j] = *(const f16x8*)&sB[(wc + j * 16 + frow) * 32 + fsl];
#pragma unroll
    for (int i = 0; i < 4; ++i)
#pragma unroll
        for (int j = 0; j < 4; ++j)
            acc[i][j] = __builtin_amdgcn_mfma_f32_16x16x32_f16(af[i], bf[j], acc[i][j], 0, 0, 0);
}

// ---------------------------------------------------------------------------
// Tile GEMM core: 128x128 tile, 4 waves 2x2, TRIPLE-buffered 32-col chunks
// with depth-2 prefetch and counted vmcnt (T3/T4-lite):
//   iter kc: s_waitcnt vmcnt(4)   <- chunk kc's 4 DMA writes landed;
//                                    chunk kc+1's stay IN FLIGHT
//            s_barrier            <- all waves' writes visible
//            issue chunk kc+2     <- into buf freed at iter kc-1
//            ds_read+MFMA chunk kc
// Each chunk gets ~2 compute phases of in-flight time; the wave never
// drains vmcnt to 0 in steady state.
// ---------------------------------------------------------------------------
DEV void gemm_tile_lds(const f16* __restrict__ A, int lda,
                       const f16* __restrict__ Bt, int K,
                       int m0, int n0,
                       f16* __restrict__ sA, f16* __restrict__ sB,  // [3*4096]
                       f32x4 (&acc)[4][4])
{
    const int tid = threadIdx.x;
    const int w = tid >> 6, lane = tid & 63;
    const int arow = lane >> 2;
    const int achk = swz(arow, lane & 3) * 8;
    const int frow = lane & 15, l4 = lane >> 4;
    const int fsl = swz(frow, l4) * 8;
    const int wr = (w >> 1) * 64, wc = (w & 1) * 64;
    const int nch = K >> 5;

    tile_load_chunk(A, lda, Bt, K, m0, n0, 0, sA, sB, w, arow, achk);
    if (nch > 1)
        tile_load_chunk(A, lda, Bt, K, m0, n0, 32, sA + 4096, sB + 4096, w, arow, achk);

    int cb = 0, lb = 2;
    for (int kc = 0; kc < nch; ++kc) {
        if (kc + 1 < nch) asm volatile("s_waitcnt vmcnt(4)" ::: "memory");
        else              asm volatile("s_waitcnt vmcnt(0)" ::: "memory");
        __builtin_amdgcn_s_barrier();
        if (kc + 2 < nch)
            tile_load_chunk(A, lda, Bt, K, m0, n0, (kc + 2) * 32,
                            sA + lb * 4096, sB + lb * 4096, w, arow, achk);
        tile_compute_chunk(sA + cb * 4096, sB + cb * 4096, acc, wr, wc, frow, fsl);
        cb = (cb == 2) ? 0 : cb + 1;
        lb = (lb == 2) ? 0 : lb + 1;
    }
}

// ---------------------------------------------------------------------------
// LSTM step core (f16 MFMA): gates = A @ Wt^T (+bias), cell update.
// c-state prefetched before the K-loop. bx/by from XCD-swizzled id.
// ---------------------------------------------------------------------------
DEV void lstm_step_core(
    f16* __restrict__ sA, f16* __restrict__ sB,   // each [3*4096] f16
    int bx, int by,
    const f16* __restrict__ A, int lda, int K,
    const f16* __restrict__ Wt,
    const float* __restrict__ bias4,
    float* __restrict__ c_state,
    f16* __restrict__ hA, int ldhA, int offhA,
    f16* __restrict__ hB, int ldhB, int offhB,
    const float* __restrict__ xsrc, int tnext,
    int M)
{
    const int tid = threadIdx.x;
    const int w = tid >> 6, lane = tid & 63;
    const int m0 = bx * 128, n0 = by * 128;
    const int wr = (w >> 1) * 64;

    // prefetch c-state (epilogue inputs) — K-loop covers the latency.
    const int u = by * 32 + (w & 1) * 16 + (lane & 15);
    const int rbase = m0 + wr + (lane >> 4) * 4;
    float cold[4][4];
#pragma unroll
    for (int i = 0; i < 4; ++i)
#pragma unroll
        for (int r = 0; r < 4; ++r)
            cold[i][r] = c_state[(size_t)(rbase + i * 16 + r) * 256 + u];

    f32x4 acc[4][4] = {};
    gemm_tile_lds(A, lda, Wt, K, m0, n0, sA, sB, acc);

    // epilogue: lane owns unit u, acc[i][j][r] = gate j of row m
    const float4 bb = *(const float4*)&bias4[u * 4];
#pragma unroll
    for (int i = 0; i < 4; ++i) {
#pragma unroll
        for (int r = 0; r < 4; ++r) {
            int m = rbase + i * 16 + r;
            if (m < M) {
                float gi = sigmoidf_(acc[i][0][r] + bb.x);
                float gf = sigmoidf_(acc[i][1][r] + bb.y);
                float gg = tanhf2_(acc[i][2][r] + bb.z);
                float go = sigmoidf_(acc[i][3][r] + bb.w);
                float cn = gf * cold[i][r] + gi * gg;
                c_state[(size_t)m * 256 + u] = cn;
                f16 h = (f16)(go * tanhf2_(cn));
                hA[(size_t)m * ldhA + offhA + u] = h;
                if (hB) hB[(size_t)m * ldhB + offhB + u] = h;
            }
        }
    }
    // layer0 blocks (by==0) stage x_{t+1} into A0next cols 0..15
    if (xsrc && by == 0) {
        int row = tid >> 1, fb = (tid & 1) * 8;
        int m = m0 + row;
        if (m < M) {
            const float* xp = xsrc + (size_t)m * 960 + tnext * 16 + fb;
            f16* dp = hB + (size_t)m * ldhB + fb;
#pragma unroll
            for (int q = 0; q < 8; ++q) dp[q] = (f16)xp[q];
        }
    }
}

// solo (single-layer) LSTM step. Grid: mtPad8*8 linear, XCD-swizzled:
// l%8 = x%8 -> all 8 y-blocks of one x-tile land on one XCD (A/c L2 locality).
__global__ __launch_bounds__(256) void lstm_mfma_kernel(
    const f16* __restrict__ A, int lda, int K,
    const f16* __restrict__ Wt, const float* __restrict__ bias4,
    float* __restrict__ c_state,
    f16* __restrict__ hA, int ldhA, int offhA,
    f16* __restrict__ hB, int ldhB, int offhB,
    const float* __restrict__ xsrc, int tnext, int M, int mtiles)
{
    __shared__ __align__(16) f16 sA[3 * 4096];
    __shared__ __align__(16) f16 sB[3 * 4096];
    const int l = blockIdx.x;
    const int xcd = l & 7, q = l >> 3;
    const int y = q & 7, xhi = q >> 3;
    const int x = xhi * 8 + xcd;
    if (x >= mtiles) return;
    lstm_step_core(sA, sB, x, y, A, lda, K, Wt, bias4, c_state,
                   hA, ldhA, offhA, hB, ldhB, offhB, xsrc, tnext, M);
}

// merged: z=0 -> layer1(t), z=1 -> layer0(t+1). All 16 (y,z) blocks of one
// x-tile share an XCD.
__global__ __launch_bounds__(256) void lstm_dual_kernel(
    const f16* __restrict__ A1, const f16* __restrict__ W1t,
    const float* __restrict__ b41, float* __restrict__ c1,
    f16* __restrict__ h1A, int ldh1A, int offh1A,
    const f16* __restrict__ A0, const f16* __restrict__ W0t,
    const float* __restrict__ b40, float* __restrict__ c0,
    f16* __restrict__ h0A, int ldh0A, int offh0A,
    f16* __restrict__ h0B, int ldh0B, int offh0B,
    const float* __restrict__ xsrc, int tnext, int M, int mtiles)
{
    __shared__ __align__(16) f16 sA[3 * 4096];
    __shared__ __align__(16) f16 sB[3 * 4096];
    const int l = blockIdx.x;
    const int xcd = l & 7, q = l >> 3;
    const int yz = q & 15, xhi = q >> 4;
    const int x = xhi * 8 + xcd;
    if (x >= mtiles) return;
    const int y = yz & 7, z = yz >> 3;
    if (z == 0)
        lstm_step_core(sA, sB, x, y, A1, 512, 512, W1t, b41, c1,
                       h1A, ldh1A, offh1A, nullptr, 0, 0, nullptr, 0, M);
    else
        lstm_step_core(sA, sB, x, y, A0, 288, 288, W0t, b40, c0,
                       h0A, ldh0A, offh0A, h0B, ldh0B, offh0B, xsrc, tnext, M);
}

// dual-B variant: y<4 -> (Btl,biasl,Cl), y>=4 -> (Btr,biasr,Cr). fp16 out.
__global__ __launch_bounds__(256) void gemm16_dual_kernel(
    const f16* __restrict__ A, int lda,
    const f16* __restrict__ Btl, const f16* __restrict__ Btr, int K,
    const float* __restrict__ biasl, const float* __restrict__ biasr,
    f16* __restrict__ Cl, f16* __restrict__ Cr, int ldc, int M)
{
    __shared__ __align__(16) f16 sA[3 * 4096];
    __shared__ __align__(16) f16 sB[3 * 4096];
    const int side = blockIdx.y >> 2;
    const f16* Bt = side ? Btr : Btl;
    const float* bias = side ? biasr : biasl;
    f16* C16 = side ? Cr : Cl;
    const int tid = threadIdx.x;
    const int w = tid >> 6, lane = tid & 63;
    const int m0 = blockIdx.x * 128, n0 = (blockIdx.y & 3) * 128;
    const int wr = (w >> 1) * 64, wcn = (w & 1) * 64;

    f32x4 acc[4][4] = {};
    gemm_tile_lds(A, lda, Bt, K, m0, n0, sA, sB, acc);

    const int rbase = m0 + wr + (lane >> 4) * 4;
#pragma unroll
    for (int i = 0; i < 4; ++i) {
#pragma unroll
        for (int r = 0; r < 4; ++r) {
            int m = rbase + i * 16 + r;
            if (m >= M) continue;
#pragma unroll
            for (int j = 0; j < 4; ++j) {
                int n = n0 + wcn + j * 16 + (lane & 15);
                float v = acc[i][j][r] + bias[n];
                C16[(size_t)m * ldc + n] = (f16)v;
            }
        }
    }
}

// Fused fc1+fc2: per row m, out[m] += sum_n relu(A@Wt^T + b1)[m,n] * w2[n].
// Each block covers 128 cols; per thread: partial over its 4 j-cols, then a
// 16-lane shfl reduce (lanes sharing row m), one atomicAdd per (row, wave).
// 8 atomics per row total (2 wc-waves x 4 y-blocks) -> negligible contention.
// Removes the 20MB hfc1 round-trip and the fc2 launch entirely.
__global__ __launch_bounds__(256) void gemm16_fc2_kernel(
    const f16* __restrict__ A, int lda,
    const f16* __restrict__ Bt, int K,
    const float* __restrict__ bias, const float* __restrict__ w2,
    float* __restrict__ out, int M)
{
    __shared__ __align__(16) f16 sA[3 * 4096];
    __shared__ __align__(16) f16 sB[3 * 4096];
    const int tid = threadIdx.x;
    const int w = tid >> 6, lane = tid & 63;
    const int m0 = blockIdx.x * 128, n0 = blockIdx.y * 128;
    const int wr = (w >> 1) * 64, wcn = (w & 1) * 64;

    f32x4 acc[4][4] = {};
    gemm_tile_lds(A, lda, Bt, K, m0, n0, sA, sB, acc);

    float bv[4], wv[4];
#pragma unroll
    for (int j = 0; j < 4; ++j) {
        int n = n0 + wcn + j * 16 + (lane & 15);
        bv[j] = bias[n];
        wv[j] = w2[n];
    }

    const int rbase = m0 + wr + (lane >> 4) * 4;
#pragma unroll
    for (int i = 0; i < 4; ++i) {
#pragma unroll
        for (int r = 0; r < 4; ++r) {
            float part = 0.f;
#pragma unroll
            for (int j = 0; j < 4; ++j) {
                float v = fmaxf(acc[i][j][r] + bv[j], 0.f);
                part = fmaf(v, wv[j], part);
            }
            part += __shfl_xor(part, 1);
            part += __shfl_xor(part, 2);
            part += __shfl_xor(part, 4);
            part += __shfl_xor(part, 8);
            int m = rbase + i * 16 + r;
            if ((lane & 15) == 0 && m < M) atomicAdd(&out[m], part);
        }
    }
}

// ---------------------------------------------------------------------------
// Edge preprocessing
// ---------------------------------------------------------------------------
__global__ void mean_sum_kernel(const float* __restrict__ a, int n, float* __restrict__ out) {
    __shared__ float s[256];
    float loc = 0.f;
    for (int i = blockIdx.x * 256 + threadIdx.x; i < n; i += gridDim.x * 256) loc += a[i];
    s[threadIdx.x] = loc;
    __syncthreads();
    for (int off = 128; off; off >>= 1) {
        if (threadIdx.x < off) s[threadIdx.x] += s[threadIdx.x + off];
        __syncthreads();
    }
    if (threadIdx.x == 0) atomicAdd(out, s[0]);
}

__global__ void hist_kernel(const int* __restrict__ ei, int Ne, int Nn,
                            int* __restrict__ counts) {
    int e = blockIdx.x * 256 + threadIdx.x;
    if (e >= Ne + Nn) return;
    int d = (e < Ne) ? ei[Ne + e] : (e - Ne);
    atomicAdd(&counts[d], 1);
}

__global__ void scan_kernel(const int* __restrict__ counts, int* __restrict__ offsets, int n) {
    __shared__ int s[256];
    int tid = threadIdx.x;
    int chunk = (n + 255) / 256;
    int b = tid * chunk;
    int loc = 0;
    for (int j = 0; j < chunk; ++j) { int i = b + j; if (i < n) loc += counts[i]; }
    s[tid] = loc;
    __syncthreads();
    for (int off = 1; off < 256; off <<= 1) {
        int v = (tid >= off) ? s[tid - off] : 0;
        __syncthreads();
        s[tid] += v;
        __syncthreads();
    }
    int run = (tid == 0) ? 0 : s[tid - 1];
    for (int j = 0; j < chunk; ++j) {
        int i = b + j;
        if (i < n) { offsets[i] = run; run += counts[i]; }
    }
    if (tid == 255) offsets[n] = run;
}

__global__ void scatter_kernel(const int* __restrict__ ei, const float* __restrict__ ea,
                               const float* __restrict__ sump, float inv_ne, int Ne, int Nn,
                               int* __restrict__ cursor, int* __restrict__ src_sorted,
                               float* __restrict__ ea_sorted) {
    int e = blockIdx.x * 256 + threadIdx.x;
    if (e >= Ne + Nn) return;
    int s, d; float a;
    if (e < Ne) { s = ei[e]; d = ei[Ne + e]; a = ea[e]; }
    else        { s = e - Ne; d = s; a = sump[0] * inv_ne; }
    int pos = atomicAdd(&cursor[d], 1);
    src_sorted[pos] = s;
    ea_sorted[pos] = a;
}

// ---------------------------------------------------------------------------
// GATv2 fused attention + aggregation, online softmax, edges split across
// the 4 waves. One block per dst node. Each WAVE covers all 512 cols
// (64 lanes x 8 cols; head h = lane>>3 is an 8-lane group -> logit reduce
// is 3 shfl_xor). Wave w processes edges beg+w, beg+w+4, ... with its own
// online-softmax state (defer-max THR=8); states merge exactly through LDS
// at the end via exp(m_w - M) weights. Depth-2 gather prefetch.
// ---------------------------------------------------------------------------
__global__ __launch_bounds__(256) void gat_fused_kernel(
    const f16* __restrict__ xl, const f16* __restrict__ xr,
    const float* __restrict__ we, const float* __restrict__ att,
    const float* __restrict__ bias,
    const int* __restrict__ offsets, const int* __restrict__ src_sorted,
    const float* __restrict__ ea_sorted,
    f16* __restrict__ out, int ldo, int N)
{
    __shared__ float s_acc[8][4][64];   // [k][wave][lane]
    __shared__ float s_m[4][64];
    __shared__ float s_den[4][64];
    const int i = blockIdx.x;
    const int tid = threadIdx.x;
    const int w = tid >> 6, lane = tid & 63;
    const int c8 = lane * 8;

    f16x8 xrv = *(const f16x8*)&xr[(size_t)i * 512 + c8];
    float xr_[8], we_[8], at_[8];
#pragma unroll
    for (int k = 0; k < 8; ++k) xr_[k] = (float)xrv[k];
    *(float4*)&we_[0] = *(const float4*)&we[c8];
    *(float4*)&we_[4] = *(const float4*)&we[c8 + 4];
    *(float4*)&at_[0] = *(const float4*)&att[c8];
    *(float4*)&at_[4] = *(const float4*)&att[c8 + 4];

    const int beg = offsets[i], end = offsets[i + 1];

    float m = -1e30f, den = 0.f;
    float acc[8] = {};

    int e = beg + w;
    float a_c = 0.f, a_n = 0.f;
    f16x8 xv_c = {}, xv_n = {};
    if (e < end) {
        a_c = ea_sorted[e];
        xv_c = *(const f16x8*)&xl[(size_t)src_sorted[e] * 512 + c8];
    }
    if (e + 4 < end) {
        a_n = ea_sorted[e + 4];
        xv_n = *(const f16x8*)&xl[(size_t)src_sorted[e + 4] * 512 + c8];
    }
    for (; e < end; e += 4) {
        float a = a_c; f16x8 xv = xv_c;
        a_c = a_n; xv_c = xv_n;
        if (e + 8 < end) {
            int sn = src_sorted[e + 8];
            a_n = ea_sorted[e + 8];
            xv_n = *(const f16x8*)&xl[(size_t)sn * 512 + c8];
        }
        float x[8];
        float p = 0.f;
#pragma unroll
        for (int k = 0; k < 8; ++k) {
            x[k] = (float)xv[k];
            float v = x[k] + xr_[k] + a * we_[k];
            v = (v > 0.f) ? v : 0.2f * v;
            p = fmaf(v, at_[k], p);
        }
        p += __shfl_xor(p, 1);
        p += __shfl_xor(p, 2);
        p += __shfl_xor(p, 4);
        if (__all(p <= m + 8.f)) {
            float wg = __expf(p - m);
            den += wg;
#pragma unroll
            for (int k = 0; k < 8; ++k) acc[k] = fmaf(wg, x[k], acc[k]);
        } else {
            float mn = fmaxf(m, p);
            float r  = __expf(m - mn);
            float wg = __expf(p - mn);
            den = den * r + wg;
#pragma unroll
            for (int k = 0; k < 8; ++k) acc[k] = fmaf(acc[k], r, wg * x[k]);
            m = mn;
        }
    }

    s_m[w][lane] = m;
    s_den[w][lane] = den;
#pragma unroll
    for (int k = 0; k < 8; ++k) s_acc[k][w][lane] = acc[k];
    __syncthreads();

    const int c2 = tid * 2;
    const int l = c2 >> 3;
    const int k0 = c2 & 7;
    float m0 = s_m[0][l], m1 = s_m[1][l], m2 = s_m[2][l], m3 = s_m[3][l];
    float M = fmaxf(fmaxf(m0, m1), fmaxf(m2, m3));
    float e0 = __expf(m0 - M), e1 = __expf(m1 - M);
    float e2 = __expf(m2 - M), e3 = __expf(m3 - M);
    float D = s_den[0][l] * e0 + s_den[1][l] * e1 + s_den[2][l] * e2 + s_den[3][l] * e3;
    float A0 = s_acc[k0][0][l] * e0 + s_acc[k0][1][l] * e1
             + s_acc[k0][2][l] * e2 + s_acc[k0][3][l] * e3;
    float A1 = s_acc[k0 + 1][0][l] * e0 + s_acc[k0 + 1][1][l] * e1
             + s_acc[k0 + 1][2][l] * e2 + s_acc[k0 + 1][3][l] * e3;
    float rD = 1.f / D;
    float v0 = A0 * rD + bias[c2];
    float v1 = A1 * rD + bias[c2 + 1];
    v0 = (v0 > 0.f) ? v0 : __expf(v0) - 1.f;
    v1 = (v1 > 0.f) ? v1 : __expf(v1) - 1.f;
    f16x2 ov; ov.x = (f16)v0; ov.y = (f16)v1;
    *(f16x2*)&out[(size_t)i * ldo + c2] = ov;
}

// ---------------------------------------------------------------------------
extern "C" void kernel_launch(void* const* d_in, const int* in_sizes, int n_in,
                              void* d_out, int out_size, void* d_ws, size_t ws_size,
                              hipStream_t stream) {
    const float* x_seq     = (const float*)d_in[0];
    const int*   edge_index= (const int*)d_in[1];
    const float* edge_attr = (const float*)d_in[2];
    const float* w_ih0 = (const float*)d_in[3];
    const float* w_hh0 = (const float*)d_in[4];
    const float* b_ih0 = (const float*)d_in[5];
    const float* b_hh0 = (const float*)d_in[6];
    const float* w_ih1 = (const float*)d_in[7];
    const float* w_hh1 = (const float*)d_in[8];
    const float* b_ih1 = (const float*)d_in[9];
    const float* b_hh1 = (const float*)d_in[10];
    const float* g0_wl = (const float*)d_in[11];
    const float* g0_bl = (const float*)d_in[12];
    const float* g0_wr = (const float*)d_in[13];
    const float* g0_br = (const float*)d_in[14];
    const float* g0_we = (const float*)d_in[15];
    const float* g0_att= (const float*)d_in[16];
    const float* g0_bias=(const float*)d_in[17];
    const float* g1_wl = (const float*)d_in[18];
    const float* g1_bl = (const float*)d_in[19];
    const float* g1_wr = (const float*)d_in[20];
    const float* g1_br = (const float*)d_in[21];
    const float* g1_we = (const float*)d_in[22];
    const float* g1_att= (const float*)d_in[23];
    const float* g1_bias=(const float*)d_in[24];
    const float* fc1_w = (const float*)d_in[25];
    const float* fc1_b = (const float*)d_in[26];
    const float* fc2_w = (const float*)d_in[27];
    const float* fc2_b = (const float*)d_in[28];
    float* out = (float*)d_out;

    const int Nn = in_sizes[0] / (60 * 16);   // 10000
    const int Ne = in_sizes[1] / 2;           // 320000
    const int Etot = Ne + Nn;
    const int MT = (Nn + 127) / 128;          // 79
    const int Mpad = MT * 128;                // 10112
    const int MTpad8 = ((MT + 7) / 8) * 8;    // 80

    size_t off = 0;
    auto alloc = [&](size_t bytes) -> void* {
        void* r = (char*)d_ws + off;
        off += (bytes + 255) & ~(size_t)255;
        return r;
    };
    f16* W0t   = (f16*)alloc((size_t)1024 * 288 * 2);
    f16* W1t   = (f16*)alloc((size_t)1024 * 512 * 2);
    float* b40 = (float*)alloc(1024 * 4);
    float* b41 = (float*)alloc(1024 * 4);
    f16* Wg0l  = (f16*)alloc((size_t)512 * 256 * 2);
    f16* Wg0r  = (f16*)alloc((size_t)512 * 256 * 2);
    f16* Wg1l  = (f16*)alloc((size_t)512 * 512 * 2);
    f16* Wg1r  = (f16*)alloc((size_t)512 * 512 * 2);
    f16* Wfc1  = (f16*)alloc((size_t)512 * 768 * 2);
    f16* A0b[2]; A0b[0] = (f16*)alloc((size_t)Mpad * 288 * 2);
                 A0b[1] = (f16*)alloc((size_t)Mpad * 288 * 2);
    f16* A1b[2]; A1b[0] = (f16*)alloc((size_t)Mpad * 512 * 2);
                 A1b[1] = (f16*)alloc((size_t)Mpad * 512 * 2);
    float* c0  = (float*)alloc((size_t)Mpad * 256 * 4);
    float* c1  = (float*)alloc((size_t)Mpad * 256 * 4);
    f16* fused = (f16*)alloc((size_t)Mpad * 768 * 2);
    f16* xlbuf = (f16*)alloc((size_t)Mpad * 512 * 2);
    f16* xrbuf = (f16*)alloc((size_t)Mpad * 512 * 2);
    f16* gbuf  = (f16*)alloc((size_t)Mpad * 512 * 2);
    int* counts  = (int*)alloc((size_t)Nn * 4);
    int* offsets = (int*)alloc((size_t)(Nn + 1) * 4);
    int* cursor  = (int*)alloc((size_t)Nn * 4);
    int* src_sorted = (int*)alloc((size_t)Etot * 4);
    float* ea_sorted = (float*)alloc((size_t)Etot * 4);
    float* meanp = (float*)alloc(256);

    // ---- weight / state prep ----
    prep_w0_kernel<<<dim3((1024 * 288 + 255) / 256), 256, 0, stream>>>(w_ih0, w_hh0, W0t);
    prep_w1_kernel<<<dim3((1024 * 512 + 255) / 256), 256, 0, stream>>>(w_ih1, w_hh1, W1t);
    prep_bias4_kernel<<<dim3(4), 256, 0, stream>>>(b_ih0, b_hh0, b40);
    prep_bias4_kernel<<<dim3(4), 256, 0, stream>>>(b_ih1, b_hh1, b41);
    prep_wt_kernel<<<dim3((256 * 512 + 255) / 256), 256, 0, stream>>>(g0_wl, Wg0l, 256, 512);
    prep_wt_kernel<<<dim3((256 * 512 + 255) / 256), 256, 0, stream>>>(g0_wr, Wg0r, 256, 512);
    prep_wt_kernel<<<dim3((512 * 512 + 255) / 256), 256, 0, stream>>>(g1_wl, Wg1l, 512, 512);
    prep_wt_kernel<<<dim3((512 * 512 + 255) / 256), 256, 0, stream>>>(g1_wr, Wg1r, 512, 512);
    prep_wt_kernel<<<dim3((768 * 512 + 255) / 256), 256, 0, stream>>>(fc1_w, Wfc1, 768, 512);
    hipMemsetAsync(A0b[0], 0, (size_t)Mpad * 288 * 2, stream);
    hipMemsetAsync(A0b[1], 0, (size_t)Mpad * 288 * 2, stream);
    hipMemsetAsync(A1b[0], 0, (size_t)Mpad * 512 * 2, stream);
    hipMemsetAsync(c0, 0, (size_t)Mpad * 256 * 4, stream);
    hipMemsetAsync(c1, 0, (size_t)Mpad * 256 * 4, stream);
    prep_x0_kernel<<<dim3((Nn * 16 + 255) / 256), 256, 0, stream>>>(x_seq, A0b[0], Nn);

    // ---- edge prep (CSR by dst) ----
    hipMemsetAsync(meanp, 0, 4, stream);
    hipMemsetAsync(counts, 0, (size_t)Nn * 4, stream);
    mean_sum_kernel<<<dim3(256), 256, 0, stream>>>(edge_attr, Ne, meanp);
    hist_kernel<<<dim3((Etot + 255) / 256), 256, 0, stream>>>(edge_index, Ne, Nn, counts);
    scan_kernel<<<dim3(1), 256, 0, stream>>>(counts, offsets, Nn);
    hipMemcpyAsync(cursor, offsets, (size_t)Nn * 4, hipMemcpyDeviceToDevice, stream);
    scatter_kernel<<<dim3((Etot + 255) / 256), 256, 0, stream>>>(
        edge_index, edge_attr, meanp, 1.0f / (float)Ne, Ne, Nn, cursor, src_sorted, ea_sorted);

    // ---- 2-layer LSTM, 60 steps; L1(t) and L0(t+1) co-scheduled, XCD-swizzled ----
    const int solo_grid = MTpad8 * 8;    // 640
    const int dual_grid = MTpad8 * 16;   // 1280
    // L0(0)
    lstm_mfma_kernel<<<dim3(solo_grid), 256, 0, stream>>>(
        A0b[0], 288, 288, W0t, b40, c0,
        A1b[0], 512, 0,
        A0b[1], 288, 16,
        x_seq, 1, Nn, MT);
    // merged L1(k) + L0(k+1), k = 0..58
    for (int k = 0; k < 59; ++k) {
        lstm_dual_kernel<<<dim3(dual_grid), 256, 0, stream>>>(
            A1b[k & 1], W1t, b41, c1,
            A1b[(k + 1) & 1], 512, 256,
            A0b[(k + 1) & 1], W0t, b40, c0,
            A1b[(k + 1) & 1], 512, 0,
            A0b[k & 1], 288, 16,
            (k + 1 < 59) ? x_seq : nullptr, k + 2, Nn, MT);
    }
    // L1(59): write h1_59 (node) directly into fused cols 0..255
    lstm_mfma_kernel<<<dim3(solo_grid), 256, 0, stream>>>(
        A1b[1], 512, 512, W1t, b41, c1,
        fused, 768, 0,
        nullptr, 0, 0,
        nullptr, 0, Nn, MT);

    // ---- GAT layer 1 (xl/xr in one launch) ----
    gemm16_dual_kernel<<<dim3(MT, 8), 256, 0, stream>>>(
        fused, 768, Wg0l, Wg0r, 256, g0_bl, g0_br, xlbuf, xrbuf, 512, Nn);
    gat_fused_kernel<<<dim3(Nn), 256, 0, stream>>>(
        xlbuf, xrbuf, g0_we, g0_att, g0_bias, offsets, src_sorted, ea_sorted,
        gbuf, 512, Nn);

    // ---- GAT layer 2 (output into fused cols 256..767) ----
    gemm16_dual_kernel<<<dim3(MT, 8), 256, 0, stream>>>(
        gbuf, 512, Wg1l, Wg1r, 512, g1_bl, g1_br, xlbuf, xrbuf, 512, Nn);
    gat_fused_kernel<<<dim3(Nn), 256, 0, stream>>>(
        xlbuf, xrbuf, g1_we, g1_att, g1_bias, offsets, src_sorted, ea_sorted,
        fused + 256, 768, Nn);

    // ---- fusion MLP: fc1 GEMM with fc2 fused into the epilogue ----
    out_init_kernel<<<dim3((Nn + 255) / 256), 256, 0, stream>>>(out, fc2_b, Nn);
    gemm16_fc2_kernel<<<dim3(MT, 4), 256, 0, stream>>>(
        fused, 768, Wfc1, 768, fc1_b, fc2_w, out, Nn);
}